// Round 1
// baseline (1408.135 us; speedup 1.0000x reference)
//
#include <hip/hip_runtime.h>
#include <math.h>

// EquiGroupSamplingIco — round 1: correct fp32 implementation.
// Pipeline: h -> sig(relu) -> h2 (big GEMM, fused A-gen) -> per-l w2 -> ico.
// Next round: stage-C GEMM to bf16 MFMA (fp32 accum) once threshold slack is known.

#define NBT  512      // B*T
#define F8c  16
#define F2c  64
#define GJ   455      // DIM6
#define GG   4096     // SO3 grid
#define NICO 60
#define MX   16384    // B*H*C rows of x

struct W7 { const float* p[7]; };

// ---------------- k_h: h[bt][c][i], i in [0,10) ----------------
__global__ __launch_bounds__(256) void k_h(const float* __restrict__ traj,
                                           const float* __restrict__ w1s,
                                           const float* __restrict__ w1v,
                                           float* __restrict__ h) {
  int idx = blockIdx.x * 256 + threadIdx.x;
  if (idx >= NBT * 160) return;
  int bt = idx / 160;
  int r  = idx % 160;
  int c  = r / 10;
  int i  = r % 10;
  const float* tr = traj + bt * 10;
  float val;
  if (i == 0) {
    val = tr[9] * w1s[c];                       // fan_in = 1
  } else {
    int k = i - 1, v = k / 3, m = k % 3;
    float s = 0.f;
    #pragma unroll
    for (int u = 0; u < 3; ++u) s = fmaf(tr[u * 3 + m], w1v[c * 9 + u * 3 + v], s);
    val = s * 0.57735026918962576f;             // 1/sqrt(3)
  }
  h[idx] = val;
}

// ---------------- k_tr: icoT[j][i] = ico[i][j], zero-padded to j<480 ----------------
__global__ __launch_bounds__(256) void k_tr(const float* __restrict__ ico,
                                            float* __restrict__ icoT) {
  int e = blockIdx.x * 256 + threadIdx.x;
  if (e >= 480 * NICO) return;
  int j = e / NICO, i = e % NICO;
  icoT[e] = (j < GJ) ? ico[i * GJ + j] : 0.f;
}

// ---------------- k_sigC: h2[m][j] = sum_g relu(h[m]·Din[g]) * Dout[g][j] ----------------
// M=8192, K=4096, N=455 (padded to 512). 128x128 tile, 8x8/thread, K-chunk 32.
__global__ __launch_bounds__(256) void k_sigC(const float* __restrict__ h,
                                              const float* __restrict__ Din,
                                              const float* __restrict__ Dout,
                                              float* __restrict__ h2) {
  __shared__ __align__(16) float hs[128 * 11];     // h rows, stride 11 (bank spread)
  __shared__ __align__(16) float dinS[32 * 10];
  __shared__ __align__(16) float At[32 * 132];     // sig tile, [kk][r]
  __shared__ __align__(16) float Bs[32 * 132];     // Dout tile, [kk][n]

  int tid = threadIdx.x;
  int tx = tid & 15, ty = tid >> 4;
  int m0 = blockIdx.y * 128;
  int nb = blockIdx.x * 128;
  int r0 = ty * 8, c0 = tx * 4;

  for (int e = tid; e < 1280; e += 256) {
    int r = e / 10, i = e % 10;
    hs[r * 11 + i] = h[m0 * 10 + e];
  }

  float acc[8][8];
  #pragma unroll
  for (int a = 0; a < 8; ++a)
    #pragma unroll
    for (int b = 0; b < 8; ++b) acc[a][b] = 0.f;

  for (int k0 = 0; k0 < GG; k0 += 32) {
    __syncthreads();
    for (int e = tid; e < 320; e += 256) dinS[e] = Din[k0 * 10 + e];
    #pragma unroll
    for (int it = 0; it < 16; ++it) {
      int e = tid + it * 256;
      int kk = e >> 7, n = e & 127;
      int j = nb + n;
      Bs[kk * 132 + n] = (j < GJ) ? Dout[(size_t)(k0 + kk) * GJ + j] : 0.f;
    }
    __syncthreads();
    // A-gen: sig = relu(h · Din^T)
    #pragma unroll
    for (int it = 0; it < 16; ++it) {
      int e = tid + it * 256;
      int kk = e >> 7, r = e & 127;
      const float* hr = &hs[r * 11];
      const float* dr = &dinS[kk * 10];
      float s = 0.f;
      #pragma unroll
      for (int i = 0; i < 10; ++i) s = fmaf(hr[i], dr[i], s);
      At[kk * 132 + r] = fmaxf(s, 0.f);
    }
    __syncthreads();
    #pragma unroll 8
    for (int kk = 0; kk < 32; ++kk) {
      float4 a0 = *(const float4*)&At[kk * 132 + r0];
      float4 a1 = *(const float4*)&At[kk * 132 + r0 + 4];
      float4 b0 = *(const float4*)&Bs[kk * 132 + c0];
      float4 b1 = *(const float4*)&Bs[kk * 132 + 64 + c0];
      float av[8] = {a0.x, a0.y, a0.z, a0.w, a1.x, a1.y, a1.z, a1.w};
      float bv[8] = {b0.x, b0.y, b0.z, b0.w, b1.x, b1.y, b1.z, b1.w};
      #pragma unroll
      for (int rr = 0; rr < 8; ++rr)
        #pragma unroll
        for (int cc = 0; cc < 8; ++cc)
          acc[rr][cc] = fmaf(av[rr], bv[cc], acc[rr][cc]);
    }
  }
  #pragma unroll
  for (int rr = 0; rr < 8; ++rr) {
    int m = m0 + r0 + rr;
    float* orow = h2 + (size_t)m * GJ;
    #pragma unroll
    for (int hh = 0; hh < 2; ++hh)
      #pragma unroll
      for (int cc = 0; cc < 4; ++cc) {
        int j = nb + hh * 64 + c0 + cc;
        if (j < GJ) orow[j] = acc[rr][hh * 4 + cc];
      }
  }
}

// ---------------- k_DE: per-(b,t): w2 equi-linear per l, then ico contraction ----------------
template <int D>
__device__ __forceinline__ void do_l(int tid, const float* __restrict__ w2l,
                                     const float* __restrict__ h2row,
                                     const float* __restrict__ icoT,
                                     float* __restrict__ h2sl,
                                     float* __restrict__ outlT,
                                     float* acc, int o, int g2b, int ib, bool active) {
  constexpr int D2 = D * D;
  constexpr int VH = (D + 3) / 4;
  __syncthreads();                       // previous l finished reading outlT/h2sl
  for (int e = tid; e < 16 * D2; e += 256) {
    int f = e / D2, k = e - f * D2;
    h2sl[e] = h2row[f * GJ + o + k];
  }
  __syncthreads();
  const float scl = rsqrtf(16.f * (float)D);
  for (int p = tid; p < 64 * VH; p += 256) {
    int g2 = p / VH;
    int v0 = (p - g2 * VH) * 4;
    bool ok1 = (v0 + 1) < D, ok2 = (v0 + 2) < D, ok3 = (v0 + 3) < D;
    float a[4][D];
    #pragma unroll
    for (int j = 0; j < 4; ++j)
      #pragma unroll
      for (int m = 0; m < D; ++m) a[j][m] = 0.f;
    const float* wg = w2l + g2 * D2 + v0;
    for (int f = 0; f < 16; ++f) {
      const float* hf = h2sl + f * D2;
      const float* wf = wg + f * 64 * D2;
      #pragma unroll
      for (int u = 0; u < D; ++u) {
        float w0 = wf[u * D];
        float w1 = ok1 ? wf[u * D + 1] : 0.f;
        float w2v = ok2 ? wf[u * D + 2] : 0.f;
        float w3 = ok3 ? wf[u * D + 3] : 0.f;
        #pragma unroll
        for (int m = 0; m < D; ++m) {
          float hv = hf[u * D + m];                 // wave-uniform -> LDS broadcast
          a[0][m] = fmaf(hv, w0, a[0][m]);
          a[1][m] = fmaf(hv, w1, a[1][m]);
          a[2][m] = fmaf(hv, w2v, a[2][m]);
          a[3][m] = fmaf(hv, w3, a[3][m]);
        }
      }
    }
    #pragma unroll
    for (int j = 0; j < 4; ++j) {
      if (v0 + j < D) {
        #pragma unroll
        for (int m = 0; m < D; ++m)
          outlT[((v0 + j) * D + m) * 64 + g2] = a[j][m] * scl;
      }
    }
  }
  __syncthreads();
  if (active) {
    #pragma unroll
    for (int kk = 0; kk < D2; ++kk) {
      float4 av = *(const float4*)&outlT[kk * 64 + g2b];
      float4 cv = *(const float4*)&icoT[(o + kk) * NICO + ib];   // global, L2-hot
      float avv[4] = {av.x, av.y, av.z, av.w};
      float cvv[4] = {cv.x, cv.y, cv.z, cv.w};
      #pragma unroll
      for (int rr = 0; rr < 4; ++rr)
        #pragma unroll
        for (int cc = 0; cc < 4; ++cc)
          acc[rr * 4 + cc] = fmaf(avv[rr], cvv[cc], acc[rr * 4 + cc]);
    }
  }
}

__global__ __launch_bounds__(256) void k_DE(const float* __restrict__ h2,
                                            const float* __restrict__ icoT,
                                            W7 w2, float* __restrict__ out) {
  __shared__ __align__(16) float h2sl[16 * 169];   // 10.8 KB
  __shared__ __align__(16) float outlT[169 * 64];  // 43.3 KB  (total 54.1 KB -> 2 blocks/CU)
  int bt = blockIdx.x;
  int tid = threadIdx.x;
  const float* h2row = h2 + (size_t)bt * F8c * GJ;
  float acc[16];
  #pragma unroll
  for (int q = 0; q < 16; ++q) acc[q] = 0.f;
  bool active = tid < 240;
  int tg = tid / 15, ti = tid - tg * 15;
  int g2b = tg * 4, ib = ti * 4;
  do_l<1>(tid, w2.p[0], h2row, icoT, h2sl, outlT, acc, 0,   g2b, ib, active);
  do_l<3>(tid, w2.p[1], h2row, icoT, h2sl, outlT, acc, 1,   g2b, ib, active);
  do_l<5>(tid, w2.p[2], h2row, icoT, h2sl, outlT, acc, 10,  g2b, ib, active);
  do_l<7>(tid, w2.p[3], h2row, icoT, h2sl, outlT, acc, 35,  g2b, ib, active);
  do_l<9>(tid, w2.p[4], h2row, icoT, h2sl, outlT, acc, 84,  g2b, ib, active);
  do_l<11>(tid, w2.p[5], h2row, icoT, h2sl, outlT, acc, 165, g2b, ib, active);
  do_l<13>(tid, w2.p[6], h2row, icoT, h2sl, outlT, acc, 286, g2b, ib, active);
  if (active) {
    float* orow = out + (size_t)bt * F2c * NICO;
    #pragma unroll
    for (int rr = 0; rr < 4; ++rr)
      #pragma unroll
      for (int cc = 0; cc < 4; ++cc)
        orow[(g2b + rr) * NICO + ib + cc] = acc[rr * 4 + cc];
  }
}

// ---------------- k_X: xg = x · icoT  (M=16384, K=455, N=60) ----------------
__global__ __launch_bounds__(256) void k_X(const float* __restrict__ x,
                                           const float* __restrict__ icoT,
                                           float* __restrict__ xg) {
  __shared__ __align__(16) float xs[32 * 68];
  int tid = threadIdx.x;
  int m0 = blockIdx.x * 64;
  bool active = tid < 240;
  int tg = tid / 15, ti = tid - tg * 15;
  int r0 = tg * 4, ib = ti * 4;
  float acc[16];
  #pragma unroll
  for (int q = 0; q < 16; ++q) acc[q] = 0.f;
  for (int k0 = 0; k0 < 480; k0 += 32) {
    __syncthreads();
    #pragma unroll
    for (int it = 0; it < 8; ++it) {
      int e = tid + it * 256;
      int k = e & 31, r = e >> 5;
      int kg = k0 + k;
      xs[k * 68 + r] = (kg < GJ) ? x[(size_t)(m0 + r) * GJ + kg] : 0.f;
    }
    __syncthreads();
    if (active) {
      #pragma unroll 8
      for (int k = 0; k < 32; ++k) {
        float4 a  = *(const float4*)&xs[k * 68 + r0];
        float4 cv = *(const float4*)&icoT[(k0 + k) * NICO + ib];  // zero-padded to 480 rows
        float avv[4] = {a.x, a.y, a.z, a.w};
        float cvv[4] = {cv.x, cv.y, cv.z, cv.w};
        #pragma unroll
        for (int rr = 0; rr < 4; ++rr)
          #pragma unroll
          for (int cc = 0; cc < 4; ++cc)
            acc[rr * 4 + cc] = fmaf(avv[rr], cvv[cc], acc[rr * 4 + cc]);
      }
    }
  }
  if (active) {
    #pragma unroll
    for (int rr = 0; rr < 4; ++rr)
      #pragma unroll
      for (int cc = 0; cc < 4; ++cc)
        xg[(size_t)(m0 + r0 + rr) * NICO + ib + cc] = acc[rr * 4 + cc];
  }
}

extern "C" void kernel_launch(void* const* d_in, const int* in_sizes, int n_in,
                              void* d_out, int out_size, void* d_ws, size_t ws_size,
                              hipStream_t stream) {
  const float *x = nullptr, *traj = nullptr, *w1s = nullptr, *w1v = nullptr;
  const float *Din = nullptr, *Dout = nullptr, *ico = nullptr;
  W7 w2{};
  for (int i = 0; i < n_in; ++i) {
    const float* p = (const float*)d_in[i];
    switch (in_sizes[i]) {
      case 7454720: x = p; break;
      case 5120:    traj = p; break;
      case 16:      w1s = p; break;
      case 144:     w1v = p; break;
      case 40960:   Din = p; break;
      case 1863680: Dout = p; break;
      case 27300:   ico = p; break;
      case 1024:    w2.p[0] = p; break;
      case 9216:    w2.p[1] = p; break;
      case 25600:   w2.p[2] = p; break;
      case 50176:   w2.p[3] = p; break;
      case 82944:   w2.p[4] = p; break;
      case 123904:  w2.p[5] = p; break;
      case 173056:  w2.p[6] = p; break;
      default: break;
    }
  }
  float* ws   = (float*)d_ws;
  float* h    = ws;                    // 81,920 floats
  float* h2   = ws + 81920;            // 8192*455 = 3,727,360 floats
  float* icoT = h2 + 3727360;          // 480*60 = 28,800 floats   (total ws 15.4 MB)
  float* xg    = (float*)d_out;            // 16384*60
  float* trajo = (float*)d_out + 983040;   // 512*64*60

  k_h  <<<dim3(320),    dim3(256), 0, stream>>>(traj, w1s, w1v, h);
  k_tr <<<dim3(113),    dim3(256), 0, stream>>>(ico, icoT);
  k_sigC<<<dim3(4, 64), dim3(256), 0, stream>>>(h, Din, Dout, h2);
  k_DE <<<dim3(512),    dim3(256), 0, stream>>>(h2, icoT, w2, trajo);
  k_X  <<<dim3(256),    dim3(256), 0, stream>>>(x, icoT, xg);
}

// Round 2
// 817.755 us; speedup vs baseline: 1.7220x; 1.7220x over previous
//
#include <hip/hip_runtime.h>
#include <math.h>

// EquiGroupSamplingIco — round 2: stage-C GEMM (h2 = relu(h·Din^T)·Dout) moved to
// bf16 MFMA 16x16x32. A(sig) generated in-kernel (VALU dot-10), B pre-transposed+
// converted to bf16 (DoutBT in ws) and staged via global_load_lds width=16 with an
// XOR swizzle applied on the global-address side (LDS side of global_load_lds is
// lane-forced). k_h / k_tr / k_DE / k_X unchanged from round 1.

#define NBT  512      // B*T
#define F8c  16
#define F2c  64
#define GJ   455      // DIM6
#define GG   4096     // SO3 grid
#define NICO 60
#define MX   16384    // B*H*C rows of x

typedef short bf16x8 __attribute__((ext_vector_type(8)));
typedef float f32x4  __attribute__((ext_vector_type(4)));
typedef unsigned int u32;

struct W7 { const float* p[7]; };

__device__ __forceinline__ unsigned short f2bf(float f) {
  unsigned int u = __float_as_uint(f);
  unsigned int r = (u + 0x7fffu + ((u >> 16) & 1u)) >> 16;   // RNE
  return (unsigned short)r;
}

// ---------------- k_h: h[bt][c][i], i in [0,10) ----------------
__global__ __launch_bounds__(256) void k_h(const float* __restrict__ traj,
                                           const float* __restrict__ w1s,
                                           const float* __restrict__ w1v,
                                           float* __restrict__ h) {
  int idx = blockIdx.x * 256 + threadIdx.x;
  if (idx >= NBT * 160) return;
  int bt = idx / 160;
  int r  = idx % 160;
  int c  = r / 10;
  int i  = r % 10;
  const float* tr = traj + bt * 10;
  float val;
  if (i == 0) {
    val = tr[9] * w1s[c];
  } else {
    int k = i - 1, v = k / 3, m = k % 3;
    float s = 0.f;
    #pragma unroll
    for (int u = 0; u < 3; ++u) s = fmaf(tr[u * 3 + m], w1v[c * 9 + u * 3 + v], s);
    val = s * 0.57735026918962576f;
  }
  h[idx] = val;
}

// ---------------- k_tr: icoT[j][i] = ico[i][j], zero-padded to j<480 ----------------
__global__ __launch_bounds__(256) void k_tr(const float* __restrict__ ico,
                                            float* __restrict__ icoT) {
  int e = blockIdx.x * 256 + threadIdx.x;
  if (e >= 480 * NICO) return;
  int j = e / NICO, i = e % NICO;
  icoT[e] = (j < GJ) ? ico[i * GJ + j] : 0.f;
}

// ---------------- k_bt: DoutBT[j][k] = bf16(Dout[k][j]), j padded to 512 ----------------
__global__ __launch_bounds__(256) void k_bt(const float* __restrict__ Dout,
                                            unsigned short* __restrict__ DoutBT) {
  __shared__ float t[64][65];
  int jt = blockIdx.x;           // 0..7   (512/64)
  int kt = blockIdx.y;           // 0..63  (4096/64)
  int tx = threadIdx.x & 63, ty = threadIdx.x >> 6;
  #pragma unroll
  for (int i = 0; i < 16; ++i) {
    int r = i * 4 + ty;                        // k-local
    int j = jt * 64 + tx;
    t[r][tx] = (j < GJ) ? Dout[(size_t)(kt * 64 + r) * GJ + j] : 0.f;
  }
  __syncthreads();
  #pragma unroll
  for (int i = 0; i < 16; ++i) {
    int jl = i * 4 + ty;                       // j-local
    DoutBT[(size_t)(jt * 64 + jl) * GG + kt * 64 + tx] = f2bf(t[tx][jl]);
  }
}

// ---------------- k_mm: h2[m][j] = sum_g relu(h[m]·Din[g]) * Dout[g][j] ----------------
// MT=64, NT=128, BK=64. 256 threads / 4 waves, each wave a 32x64 quadrant (2x4 tiles).
// A generated in-kernel (bf16 into swizzled LDS); B via global_load_lds from DoutBT
// with swizzle on the global side. Fragment maps (m89/m91/m120):
//   A[m=lane&15][k=quad*8+j], B[k=quad*8+j][n=lane&15], D: col=lane&15,row=quad*4+reg.
__global__ __launch_bounds__(256) void k_mm(const float* __restrict__ h,
                                            const float* __restrict__ Din,
                                            const unsigned short* __restrict__ DoutBT,
                                            float* __restrict__ h2) {
  __shared__ __align__(16) short As[64 * 64];     // 8 KB  slot(m,p) at m*64+(p^(m&7))*8
  __shared__ __align__(16) short Bs2[128 * 64];   // 16 KB slot(n,pp) at n*64+pp*8
  __shared__ __align__(16) float hs[64 * 11];
  __shared__ __align__(16) float dins[64 * 11];

  int tid = threadIdx.x;
  int lane = tid & 63, wid = tid >> 6;
  int quad = lane >> 4, lr = lane & 15;
  int wm = wid >> 1, wn = wid & 1;               // wave quadrant: m=wm*32, n=wn*64
  int m_base = blockIdx.y * 64;
  int nb = blockIdx.x;                           // N-tile (0..3)

  // stage h rows once (64 x 10, stride 11)
  for (int e = tid; e < 640; e += 256) {
    int r = e / 10, i = e - 10 * r;
    hs[r * 11 + i] = h[(size_t)m_base * 10 + e];
  }

  f32x4 acc[2][4];
  #pragma unroll
  for (int a = 0; a < 2; ++a)
    #pragma unroll
    for (int b = 0; b < 4; ++b) acc[a][b] = (f32x4){0.f, 0.f, 0.f, 0.f};

  const unsigned short* bbase = DoutBT + (size_t)nb * 128 * GG;

  for (int kc = 0; kc < GG; kc += 64) {
    __syncthreads();                             // prev chunk's MFMA reads done
    // stage Din chunk (64 x 10, stride 11)
    for (int e = tid; e < 640; e += 256) {
      int r = e / 10, i = e - 10 * r;
      dins[r * 11 + i] = Din[(size_t)(kc + r) * 10 + i];
    }
    // B: async global->LDS, 16B/lane; swizzle chosen on the global side
    #pragma unroll
    for (int it = 0; it < 4; ++it) {
      int s = wid * 256 + it * 64 + lane;        // LDS slot (lane-forced)
      int n = s >> 3, pp = s & 7;
      int p = pp ^ (n & 7);
      const unsigned short* g = bbase + (size_t)n * GG + kc + p * 8;
      __builtin_amdgcn_global_load_lds(
          (const __attribute__((address_space(1))) u32*)g,
          (__attribute__((address_space(3))) u32*)(Bs2 + (wid * 256 + it * 64) * 8),
          16, 0, 0);
    }
    __syncthreads();                             // dins visible (also drains B loads)
    // A-gen: sig = relu(h·Din^T) -> bf16, swizzled ds_write_b128
    #pragma unroll
    for (int t2 = 0; t2 < 2; ++t2) {
      int pr = tid + t2 * 256;                   // 0..511
      int m = pr >> 3, p = pr & 7;
      const float* hr = &hs[m * 11];
      float hv[10];
      #pragma unroll
      for (int i = 0; i < 10; ++i) hv[i] = hr[i];
      bf16x8 outv;
      #pragma unroll
      for (int j = 0; j < 8; ++j) {
        const float* dr = &dins[(p * 8 + j) * 11];
        float s = 0.f;
        #pragma unroll
        for (int i = 0; i < 10; ++i) s = fmaf(hv[i], dr[i], s);
        outv[j] = (short)f2bf(fmaxf(s, 0.f));
      }
      *(bf16x8*)&As[m * 64 + (p ^ (m & 7)) * 8] = outv;
    }
    __syncthreads();                             // As visible
    // MFMA: 2 k-steps x 2 m-tiles x 4 n-tiles
    #pragma unroll
    for (int ks = 0; ks < 2; ++ks) {
      int v = (ks * 4 + quad) ^ (lr & 7);        // swizzle index (same for A and B)
      bf16x8 af[2], bfr[4];
      #pragma unroll
      for (int mt = 0; mt < 2; ++mt)
        af[mt] = *(const bf16x8*)&As[(wm * 32 + mt * 16 + lr) * 64 + v * 8];
      #pragma unroll
      for (int nt = 0; nt < 4; ++nt)
        bfr[nt] = *(const bf16x8*)&Bs2[(wn * 64 + nt * 16 + lr) * 64 + v * 8];
      #pragma unroll
      for (int mt = 0; mt < 2; ++mt)
        #pragma unroll
        for (int nt = 0; nt < 4; ++nt)
          acc[mt][nt] = __builtin_amdgcn_mfma_f32_16x16x32_bf16(af[mt], bfr[nt], acc[mt][nt], 0, 0, 0);
    }
  }
  // epilogue: D col=lane&15, row=quad*4+reg
  #pragma unroll
  for (int mt = 0; mt < 2; ++mt) {
    #pragma unroll
    for (int nt = 0; nt < 4; ++nt) {
      int j = nb * 128 + wn * 64 + nt * 16 + lr;
      if (j < GJ) {
        #pragma unroll
        for (int r = 0; r < 4; ++r) {
          int m = m_base + wm * 32 + mt * 16 + quad * 4 + r;
          h2[(size_t)m * GJ + j] = acc[mt][nt][r];
        }
      }
    }
  }
}

// ---------------- k_DE: per-(b,t): w2 equi-linear per l, then ico contraction ----------------
template <int D>
__device__ __forceinline__ void do_l(int tid, const float* __restrict__ w2l,
                                     const float* __restrict__ h2row,
                                     const float* __restrict__ icoT,
                                     float* __restrict__ h2sl,
                                     float* __restrict__ outlT,
                                     float* acc, int o, int g2b, int ib, bool active) {
  constexpr int D2 = D * D;
  constexpr int VH = (D + 3) / 4;
  __syncthreads();
  for (int e = tid; e < 16 * D2; e += 256) {
    int f = e / D2, k = e - f * D2;
    h2sl[e] = h2row[f * GJ + o + k];
  }
  __syncthreads();
  const float scl = rsqrtf(16.f * (float)D);
  for (int p = tid; p < 64 * VH; p += 256) {
    int g2 = p / VH;
    int v0 = (p - g2 * VH) * 4;
    bool ok1 = (v0 + 1) < D, ok2 = (v0 + 2) < D, ok3 = (v0 + 3) < D;
    float a[4][D];
    #pragma unroll
    for (int j = 0; j < 4; ++j)
      #pragma unroll
      for (int m = 0; m < D; ++m) a[j][m] = 0.f;
    const float* wg = w2l + g2 * D2 + v0;
    for (int f = 0; f < 16; ++f) {
      const float* hf = h2sl + f * D2;
      const float* wf = wg + f * 64 * D2;
      #pragma unroll
      for (int u = 0; u < D; ++u) {
        float w0 = wf[u * D];
        float w1 = ok1 ? wf[u * D + 1] : 0.f;
        float w2v = ok2 ? wf[u * D + 2] : 0.f;
        float w3 = ok3 ? wf[u * D + 3] : 0.f;
        #pragma unroll
        for (int m = 0; m < D; ++m) {
          float hv = hf[u * D + m];
          a[0][m] = fmaf(hv, w0, a[0][m]);
          a[1][m] = fmaf(hv, w1, a[1][m]);
          a[2][m] = fmaf(hv, w2v, a[2][m]);
          a[3][m] = fmaf(hv, w3, a[3][m]);
        }
      }
    }
    #pragma unroll
    for (int j = 0; j < 4; ++j) {
      if (v0 + j < D) {
        #pragma unroll
        for (int m = 0; m < D; ++m)
          outlT[((v0 + j) * D + m) * 64 + g2] = a[j][m] * scl;
      }
    }
  }
  __syncthreads();
  if (active) {
    #pragma unroll
    for (int kk = 0; kk < D2; ++kk) {
      float4 av = *(const float4*)&outlT[kk * 64 + g2b];
      float4 cv = *(const float4*)&icoT[(o + kk) * NICO + ib];
      float avv[4] = {av.x, av.y, av.z, av.w};
      float cvv[4] = {cv.x, cv.y, cv.z, cv.w};
      #pragma unroll
      for (int rr = 0; rr < 4; ++rr)
        #pragma unroll
        for (int cc = 0; cc < 4; ++cc)
          acc[rr * 4 + cc] = fmaf(avv[rr], cvv[cc], acc[rr * 4 + cc]);
    }
  }
}

__global__ __launch_bounds__(256) void k_DE(const float* __restrict__ h2,
                                            const float* __restrict__ icoT,
                                            W7 w2, float* __restrict__ out) {
  __shared__ __align__(16) float h2sl[16 * 169];
  __shared__ __align__(16) float outlT[169 * 64];
  int bt = blockIdx.x;
  int tid = threadIdx.x;
  const float* h2row = h2 + (size_t)bt * F8c * GJ;
  float acc[16];
  #pragma unroll
  for (int q = 0; q < 16; ++q) acc[q] = 0.f;
  bool active = tid < 240;
  int tg = tid / 15, ti = tid - tg * 15;
  int g2b = tg * 4, ib = ti * 4;
  do_l<1>(tid, w2.p[0], h2row, icoT, h2sl, outlT, acc, 0,   g2b, ib, active);
  do_l<3>(tid, w2.p[1], h2row, icoT, h2sl, outlT, acc, 1,   g2b, ib, active);
  do_l<5>(tid, w2.p[2], h2row, icoT, h2sl, outlT, acc, 10,  g2b, ib, active);
  do_l<7>(tid, w2.p[3], h2row, icoT, h2sl, outlT, acc, 35,  g2b, ib, active);
  do_l<9>(tid, w2.p[4], h2row, icoT, h2sl, outlT, acc, 84,  g2b, ib, active);
  do_l<11>(tid, w2.p[5], h2row, icoT, h2sl, outlT, acc, 165, g2b, ib, active);
  do_l<13>(tid, w2.p[6], h2row, icoT, h2sl, outlT, acc, 286, g2b, ib, active);
  if (active) {
    float* orow = out + (size_t)bt * F2c * NICO;
    #pragma unroll
    for (int rr = 0; rr < 4; ++rr)
      #pragma unroll
      for (int cc = 0; cc < 4; ++cc)
        orow[(g2b + rr) * NICO + ib + cc] = acc[rr * 4 + cc];
  }
}

// ---------------- k_X: xg = x · icoT  (M=16384, K=455, N=60) ----------------
__global__ __launch_bounds__(256) void k_X(const float* __restrict__ x,
                                           const float* __restrict__ icoT,
                                           float* __restrict__ xg) {
  __shared__ __align__(16) float xs[32 * 68];
  int tid = threadIdx.x;
  int m0 = blockIdx.x * 64;
  bool active = tid < 240;
  int tg = tid / 15, ti = tid - tg * 15;
  int r0 = tg * 4, ib = ti * 4;
  float acc[16];
  #pragma unroll
  for (int q = 0; q < 16; ++q) acc[q] = 0.f;
  for (int k0 = 0; k0 < 480; k0 += 32) {
    __syncthreads();
    #pragma unroll
    for (int it = 0; it < 8; ++it) {
      int e = tid + it * 256;
      int k = e & 31, r = e >> 5;
      int kg = k0 + k;
      xs[k * 68 + r] = (kg < GJ) ? x[(size_t)(m0 + r) * GJ + kg] : 0.f;
    }
    __syncthreads();
    if (active) {
      #pragma unroll 8
      for (int k = 0; k < 32; ++k) {
        float4 a  = *(const float4*)&xs[k * 68 + r0];
        float4 cv = *(const float4*)&icoT[(k0 + k) * NICO + ib];
        float avv[4] = {a.x, a.y, a.z, a.w};
        float cvv[4] = {cv.x, cv.y, cv.z, cv.w};
        #pragma unroll
        for (int rr = 0; rr < 4; ++rr)
          #pragma unroll
          for (int cc = 0; cc < 4; ++cc)
            acc[rr * 4 + cc] = fmaf(avv[rr], cvv[cc], acc[rr * 4 + cc]);
      }
    }
  }
  if (active) {
    #pragma unroll
    for (int rr = 0; rr < 4; ++rr)
      #pragma unroll
      for (int cc = 0; cc < 4; ++cc)
        xg[(size_t)(m0 + r0 + rr) * NICO + ib + cc] = acc[rr * 4 + cc];
  }
}

extern "C" void kernel_launch(void* const* d_in, const int* in_sizes, int n_in,
                              void* d_out, int out_size, void* d_ws, size_t ws_size,
                              hipStream_t stream) {
  const float *x = nullptr, *traj = nullptr, *w1s = nullptr, *w1v = nullptr;
  const float *Din = nullptr, *Dout = nullptr, *ico = nullptr;
  W7 w2{};
  for (int i = 0; i < n_in; ++i) {
    const float* p = (const float*)d_in[i];
    switch (in_sizes[i]) {
      case 7454720: x = p; break;
      case 5120:    traj = p; break;
      case 16:      w1s = p; break;
      case 144:     w1v = p; break;
      case 40960:   Din = p; break;
      case 1863680: Dout = p; break;
      case 27300:   ico = p; break;
      case 1024:    w2.p[0] = p; break;
      case 9216:    w2.p[1] = p; break;
      case 25600:   w2.p[2] = p; break;
      case 50176:   w2.p[3] = p; break;
      case 82944:   w2.p[4] = p; break;
      case 123904:  w2.p[5] = p; break;
      case 173056:  w2.p[6] = p; break;
      default: break;
    }
  }
  float* ws   = (float*)d_ws;
  float* h    = ws;                        // 81,920 floats
  float* h2   = ws + 81920;                // 3,727,360 floats
  float* icoT = h2 + 3727360;              // 28,800 floats
  unsigned short* DoutBT = (unsigned short*)(icoT + 28800);  // 512*4096 bf16 (4 MB); ws total ~19.5 MB
  float* xg    = (float*)d_out;            // 16384*60
  float* trajo = (float*)d_out + 983040;   // 512*64*60

  k_h  <<<dim3(320),      dim3(256), 0, stream>>>(traj, w1s, w1v, h);
  k_tr <<<dim3(113),      dim3(256), 0, stream>>>(ico, icoT);
  k_bt <<<dim3(8, 64),    dim3(256), 0, stream>>>(Dout, DoutBT);
  k_mm <<<dim3(4, 128),   dim3(256), 0, stream>>>(h, Din, DoutBT, h2);
  k_DE <<<dim3(512),      dim3(256), 0, stream>>>(h2, icoT, w2, trajo);
  k_X  <<<dim3(256),      dim3(256), 0, stream>>>(x, icoT, xg);
}

// Round 3
// 403.888 us; speedup vs baseline: 3.4864x; 2.0247x over previous
//
#include <hip/hip_runtime.h>
#include <math.h>

// EquiGroupSamplingIco — round 3: entire tail moved to bf16 MFMA GEMMs.
//   k_mm   : h2 = relu(h·Din^T)·Dout   (bf16 MFMA, now emits h2 in bf16)
//   k_hT   : repack h2 -> per-l A operands [(bt,m)][(f,u)], K zero-padded
//   k_wT   : repack w2 -> per-l B operands [(g2,v)][(f,u)], scale folded in
//   k_batch: 7 per-l GEMMs in one launch (block table), scatter bf16 -> trajbf
//   k_gt   : trajo = trajbf · icoB^T   (M=32768, K=512, N=64; i<60 stored)
//   k_xg   : xg    = x      · icoB^T   (M=16384, fp32->bf16 inline staging)

#define NBT  512
#define F8c  16
#define F2c  64
#define GJ   455
#define GG   4096
#define NICO 60
#define JP   512      // padded j for trajbf / icoB

typedef short bf16x8 __attribute__((ext_vector_type(8)));
typedef float f32x4  __attribute__((ext_vector_type(4)));
typedef unsigned int u32;
typedef unsigned short ushort;

struct W7 { const float* p[7]; };

__device__ __forceinline__ ushort f2bf(float f) {
  u32 u = __float_as_uint(f);
  return (ushort)((u + 0x7fffu + ((u >> 16) & 1u)) >> 16);   // RNE
}

__device__ __forceinline__ int sel7(int l, int a0, int a1, int a2, int a3,
                                    int a4, int a5, int a6) {
  int r = a6;
  r = (l == 5) ? a5 : r; r = (l == 4) ? a4 : r; r = (l == 3) ? a3 : r;
  r = (l == 2) ? a2 : r; r = (l == 1) ? a1 : r; r = (l == 0) ? a0 : r;
  return r;
}

// ---------------- k_h ----------------
__global__ __launch_bounds__(256) void k_h(const float* __restrict__ traj,
                                           const float* __restrict__ w1s,
                                           const float* __restrict__ w1v,
                                           float* __restrict__ h) {
  int idx = blockIdx.x * 256 + threadIdx.x;
  if (idx >= NBT * 160) return;
  int bt = idx / 160, r = idx % 160, c = r / 10, i = r % 10;
  const float* tr = traj + bt * 10;
  float val;
  if (i == 0) {
    val = tr[9] * w1s[c];
  } else {
    int k = i - 1, v = k / 3, m = k % 3;
    float s = 0.f;
    #pragma unroll
    for (int u = 0; u < 3; ++u) s = fmaf(tr[u * 3 + m], w1v[c * 9 + u * 3 + v], s);
    val = s * 0.57735026918962576f;
  }
  h[idx] = val;
}

// ---------------- k_icoB: icoB[i][j] bf16, 64x512 zero-padded ----------------
__global__ __launch_bounds__(256) void k_icoB(const float* __restrict__ ico,
                                              ushort* __restrict__ icoB) {
  int e = blockIdx.x * 256 + threadIdx.x;   // 32768
  int i = e >> 9, j = e & 511;
  icoB[e] = (i < NICO && j < GJ) ? f2bf(ico[i * GJ + j]) : (ushort)0;
}

// ---------------- k_bt: DoutBT[j][k] bf16, j padded to 512 ----------------
__global__ __launch_bounds__(256) void k_bt(const float* __restrict__ Dout,
                                            ushort* __restrict__ DoutBT) {
  __shared__ float t[64][65];
  int jt = blockIdx.x, kt = blockIdx.y;
  int tx = threadIdx.x & 63, ty = threadIdx.x >> 6;
  #pragma unroll
  for (int i = 0; i < 16; ++i) {
    int r = i * 4 + ty, j = jt * 64 + tx;
    t[r][tx] = (j < GJ) ? Dout[(size_t)(kt * 64 + r) * GJ + j] : 0.f;
  }
  __syncthreads();
  #pragma unroll
  for (int i = 0; i < 16; ++i) {
    int jl = i * 4 + ty;
    DoutBT[(size_t)(jt * 64 + jl) * GG + kt * 64 + tx] = f2bf(t[tx][jl]);
  }
}

// ---------------- k_mm: big GEMM, emits h2 bf16 ----------------
__global__ __launch_bounds__(256) void k_mm(const float* __restrict__ h,
                                            const float* __restrict__ Din,
                                            const ushort* __restrict__ DoutBT,
                                            ushort* __restrict__ h2b) {
  __shared__ __align__(16) short As[64 * 64];
  __shared__ __align__(16) short Bs2[128 * 64];
  __shared__ __align__(16) float hs[64 * 11];
  __shared__ __align__(16) float dins[64 * 11];

  int tid = threadIdx.x;
  int lane = tid & 63, wid = tid >> 6;
  int quad = lane >> 4, lr = lane & 15;
  int wm = wid >> 1, wn = wid & 1;
  int m_base = blockIdx.y * 64;
  int nb = blockIdx.x;

  for (int e = tid; e < 640; e += 256) {
    int r = e / 10, i = e - 10 * r;
    hs[r * 11 + i] = h[(size_t)m_base * 10 + e];
  }

  f32x4 acc[2][4];
  #pragma unroll
  for (int a = 0; a < 2; ++a)
    #pragma unroll
    for (int b = 0; b < 4; ++b) acc[a][b] = (f32x4){0.f, 0.f, 0.f, 0.f};

  const ushort* bbase = DoutBT + (size_t)nb * 128 * GG;

  for (int kc = 0; kc < GG; kc += 64) {
    __syncthreads();
    for (int e = tid; e < 640; e += 256) {
      int r = e / 10, i = e - 10 * r;
      dins[r * 11 + i] = Din[(size_t)(kc + r) * 10 + i];
    }
    #pragma unroll
    for (int it = 0; it < 4; ++it) {
      int s = wid * 256 + it * 64 + lane;
      int n = s >> 3, pp = s & 7;
      int p = pp ^ (n & 7);
      const ushort* g = bbase + (size_t)n * GG + kc + p * 8;
      __builtin_amdgcn_global_load_lds(
          (const __attribute__((address_space(1))) u32*)g,
          (__attribute__((address_space(3))) u32*)(Bs2 + (wid * 256 + it * 64) * 8),
          16, 0, 0);
    }
    __syncthreads();
    #pragma unroll
    for (int t2 = 0; t2 < 2; ++t2) {
      int pr = tid + t2 * 256;
      int m = pr >> 3, p = pr & 7;
      const float* hr = &hs[m * 11];
      float hv[10];
      #pragma unroll
      for (int i = 0; i < 10; ++i) hv[i] = hr[i];
      bf16x8 outv;
      #pragma unroll
      for (int j = 0; j < 8; ++j) {
        const float* dr = &dins[(p * 8 + j) * 11];
        float s = 0.f;
        #pragma unroll
        for (int i = 0; i < 10; ++i) s = fmaf(hv[i], dr[i], s);
        outv[j] = (short)f2bf(fmaxf(s, 0.f));
      }
      *(bf16x8*)&As[m * 64 + (p ^ (m & 7)) * 8] = outv;
    }
    __syncthreads();
    #pragma unroll
    for (int ks = 0; ks < 2; ++ks) {
      int v = (ks * 4 + quad) ^ (lr & 7);
      bf16x8 af[2], bfr[4];
      #pragma unroll
      for (int mt = 0; mt < 2; ++mt)
        af[mt] = *(const bf16x8*)&As[(wm * 32 + mt * 16 + lr) * 64 + v * 8];
      #pragma unroll
      for (int nt = 0; nt < 4; ++nt)
        bfr[nt] = *(const bf16x8*)&Bs2[(wn * 64 + nt * 16 + lr) * 64 + v * 8];
      #pragma unroll
      for (int mt = 0; mt < 2; ++mt)
        #pragma unroll
        for (int nt = 0; nt < 4; ++nt)
          acc[mt][nt] = __builtin_amdgcn_mfma_f32_16x16x32_bf16(af[mt], bfr[nt], acc[mt][nt], 0, 0, 0);
    }
  }
  #pragma unroll
  for (int mt = 0; mt < 2; ++mt)
    #pragma unroll
    for (int nt = 0; nt < 4; ++nt) {
      int j = nb * 128 + wn * 64 + nt * 16 + lr;
      if (j < GJ) {
        #pragma unroll
        for (int r = 0; r < 4; ++r) {
          int m = m_base + wm * 32 + mt * 16 + quad * 4 + r;
          h2b[(size_t)m * GJ + j] = f2bf(acc[mt][nt][r]);
        }
      }
    }
}

// per-l constants
// d:  1,3,5,7,9,11,13   Kp: 64,64,128,128,192,192,256   o: 0,1,10,35,84,165,286
// Aoff(el): 0,32768,131072,458752,917504,1802240,2883584   (total 4587520)
// Boff(el): 0,4096,16384,57344,114688,225280,360448        (total 573440)
// blocks cum: 8,80,280,672,1320,2288,3640
// elems/bt cum (k_hT): 64,256,896,1792,3520,5632,8960

// ---------------- k_hT: h2b -> per-l A operand layout ----------------
__global__ __launch_bounds__(256) void k_hT(const ushort* __restrict__ h2b,
                                            ushort* __restrict__ Abuf) {
  __shared__ ushort hsl[7280];
  int bt = blockIdx.x, tid = threadIdx.x;
  for (int e = tid; e < 7280; e += 256) hsl[e] = h2b[(size_t)bt * 7280 + e];
  __syncthreads();
  for (int e = tid; e < 8960; e += 256) {
    int l = (e >= 64) + (e >= 256) + (e >= 896) + (e >= 1792) + (e >= 3520) + (e >= 5632);
    int base = sel7(l, 0, 64, 256, 896, 1792, 3520, 5632);
    int d    = sel7(l, 1, 3, 5, 7, 9, 11, 13);
    int Kp   = sel7(l, 64, 64, 128, 128, 192, 192, 256);
    int o    = sel7(l, 0, 1, 10, 35, 84, 165, 286);
    int Aoff = sel7(l, 0, 32768, 131072, 458752, 917504, 1802240, 2883584);
    int local = e - base;
    int m = local / Kp, kcol = local - m * Kp;
    ushort val = 0;
    if (kcol < 16 * d) {
      int f = kcol / d, u = kcol - f * d;
      val = hsl[f * GJ + o + u * d + m];
    }
    Abuf[(size_t)Aoff + ((size_t)bt * d + m) * Kp + kcol] = val;
  }
}

// ---------------- k_wT: w2 -> per-l B operand layout (scale folded) ----------------
__global__ __launch_bounds__(256) void k_wT(W7 w2, ushort* __restrict__ Bbuf) {
  int ee = blockIdx.x * 256 + threadIdx.x;   // 573440 total
  if (ee >= 573440) return;
  int l = (ee >= 4096) + (ee >= 16384) + (ee >= 57344) + (ee >= 114688) +
          (ee >= 225280) + (ee >= 360448);
  int base = sel7(l, 0, 4096, 16384, 57344, 114688, 225280, 360448);
  int d    = sel7(l, 1, 3, 5, 7, 9, 11, 13);
  int Kp   = sel7(l, 64, 64, 128, 128, 192, 192, 256);
  int local = ee - base;
  int row = local / Kp, kcol = local - row * Kp;
  int g2 = row / d, v = row - g2 * d;
  ushort val = 0;
  if (kcol < 16 * d) {
    int f = kcol / d, u = kcol - f * d;
    const float* wl = w2.p[l];
    float scl = rsqrtf(16.f * (float)d);
    val = f2bf(wl[(((size_t)f * 64 + g2) * d + u) * d + v] * scl);
  }
  Bbuf[ee] = val;
}

// ---------------- k_batch: 7 per-l GEMMs, scatter into trajbf ----------------
__global__ __launch_bounds__(256) void k_batch(const ushort* __restrict__ Abuf,
                                               const ushort* __restrict__ Bbuf,
                                               ushort* __restrict__ trajbf) {
  __shared__ __align__(16) short As[64 * 64];
  __shared__ __align__(16) short Bs[64 * 64];
  int bid = blockIdx.x;
  int l = (bid >= 8) + (bid >= 80) + (bid >= 280) + (bid >= 672) +
          (bid >= 1320) + (bid >= 2288);
  int bbase = sel7(l, 0, 8, 80, 280, 672, 1320, 2288);
  int d     = sel7(l, 1, 3, 5, 7, 9, 11, 13);
  int Kp    = sel7(l, 64, 64, 128, 128, 192, 192, 256);
  int o     = sel7(l, 0, 1, 10, 35, 84, 165, 286);
  int Aoff  = sel7(l, 0, 32768, 131072, 458752, 917504, 1802240, 2883584);
  int Boff  = sel7(l, 0, 4096, 16384, 57344, 114688, 225280, 360448);
  int t = bid - bbase;
  int mtile = t / d, ntile = t - mtile * d;

  int tid = threadIdx.x;
  int lane = tid & 63, wid = tid >> 6;
  int quad = lane >> 4, lr = lane & 15;
  int wm = wid >> 1, wn = wid & 1;

  f32x4 acc[2][2];
  #pragma unroll
  for (int a = 0; a < 2; ++a)
    #pragma unroll
    for (int b = 0; b < 2; ++b) acc[a][b] = (f32x4){0.f, 0.f, 0.f, 0.f};

  const ushort* Ab = Abuf + Aoff;
  const ushort* Bb = Bbuf + Boff;

  for (int kc = 0; kc < Kp; kc += 64) {
    __syncthreads();
    #pragma unroll
    for (int it = 0; it < 2; ++it) {
      int s0 = (wid * 2 + it) * 64;
      int s = s0 + lane;
      int r = s >> 3, p8 = s & 7, p = p8 ^ (r & 7);
      const ushort* ga = Ab + (size_t)(mtile * 64 + r) * Kp + kc + p * 8;
      __builtin_amdgcn_global_load_lds(
          (const __attribute__((address_space(1))) u32*)ga,
          (__attribute__((address_space(3))) u32*)(As + s0 * 8), 16, 0, 0);
      const ushort* gb = Bb + (size_t)(ntile * 64 + r) * Kp + kc + p * 8;
      __builtin_amdgcn_global_load_lds(
          (const __attribute__((address_space(1))) u32*)gb,
          (__attribute__((address_space(3))) u32*)(Bs + s0 * 8), 16, 0, 0);
    }
    __syncthreads();
    #pragma unroll
    for (int ks = 0; ks < 2; ++ks) {
      int v = (ks * 4 + quad) ^ (lr & 7);
      bf16x8 af[2], bfv[2];
      #pragma unroll
      for (int mt = 0; mt < 2; ++mt)
        af[mt] = *(const bf16x8*)&As[(wm * 32 + mt * 16 + lr) * 64 + v * 8];
      #pragma unroll
      for (int nt = 0; nt < 2; ++nt)
        bfv[nt] = *(const bf16x8*)&Bs[(wn * 32 + nt * 16 + lr) * 64 + v * 8];
      #pragma unroll
      for (int mt = 0; mt < 2; ++mt)
        #pragma unroll
        for (int nt = 0; nt < 2; ++nt)
          acc[mt][nt] = __builtin_amdgcn_mfma_f32_16x16x32_bf16(af[mt], bfv[nt], acc[mt][nt], 0, 0, 0);
    }
  }
  #pragma unroll
  for (int mt = 0; mt < 2; ++mt)
    #pragma unroll
    for (int nt = 0; nt < 2; ++nt)
      #pragma unroll
      for (int r = 0; r < 4; ++r) {
        int Mrow = mtile * 64 + wm * 32 + mt * 16 + quad * 4 + r;
        int Ncol = ntile * 64 + wn * 32 + nt * 16 + lr;
        int bt = Mrow / d, m = Mrow - bt * d;
        int g2 = Ncol / d, v = Ncol - g2 * d;
        trajbf[(size_t)(bt * 64 + g2) * JP + o + v * d + m] = f2bf(acc[mt][nt][r]);
      }
}

// ---------------- k_gt: trajo = trajbf · icoB^T ----------------
__global__ __launch_bounds__(256) void k_gt(const ushort* __restrict__ trajbf,
                                            const ushort* __restrict__ icoB,
                                            float* __restrict__ out) {
  __shared__ __align__(16) short As[64 * 64];
  __shared__ __align__(16) short Bs[64 * 64];
  int mtile = blockIdx.x;
  int tid = threadIdx.x;
  int lane = tid & 63, wid = tid >> 6;
  int quad = lane >> 4, lr = lane & 15;
  int wm = wid >> 1, wn = wid & 1;
  f32x4 acc[2][2];
  #pragma unroll
  for (int a = 0; a < 2; ++a)
    #pragma unroll
    for (int b = 0; b < 2; ++b) acc[a][b] = (f32x4){0.f, 0.f, 0.f, 0.f};
  for (int kc = 0; kc < JP; kc += 64) {
    __syncthreads();
    #pragma unroll
    for (int it = 0; it < 2; ++it) {
      int s0 = (wid * 2 + it) * 64;
      int s = s0 + lane;
      int r = s >> 3, p8 = s & 7, p = p8 ^ (r & 7);
      const ushort* ga = trajbf + (size_t)(mtile * 64 + r) * JP + kc + p * 8;
      __builtin_amdgcn_global_load_lds(
          (const __attribute__((address_space(1))) u32*)ga,
          (__attribute__((address_space(3))) u32*)(As + s0 * 8), 16, 0, 0);
      const ushort* gb = icoB + (size_t)r * JP + kc + p * 8;
      __builtin_amdgcn_global_load_lds(
          (const __attribute__((address_space(1))) u32*)gb,
          (__attribute__((address_space(3))) u32*)(Bs + s0 * 8), 16, 0, 0);
    }
    __syncthreads();
    #pragma unroll
    for (int ks = 0; ks < 2; ++ks) {
      int v = (ks * 4 + quad) ^ (lr & 7);
      bf16x8 af[2], bfv[2];
      #pragma unroll
      for (int mt = 0; mt < 2; ++mt)
        af[mt] = *(const bf16x8*)&As[(wm * 32 + mt * 16 + lr) * 64 + v * 8];
      #pragma unroll
      for (int nt = 0; nt < 2; ++nt)
        bfv[nt] = *(const bf16x8*)&Bs[(wn * 32 + nt * 16 + lr) * 64 + v * 8];
      #pragma unroll
      for (int mt = 0; mt < 2; ++mt)
        #pragma unroll
        for (int nt = 0; nt < 2; ++nt)
          acc[mt][nt] = __builtin_amdgcn_mfma_f32_16x16x32_bf16(af[mt], bfv[nt], acc[mt][nt], 0, 0, 0);
    }
  }
  #pragma unroll
  for (int mt = 0; mt < 2; ++mt)
    #pragma unroll
    for (int nt = 0; nt < 2; ++nt) {
      int i = wn * 32 + nt * 16 + lr;
      if (i < NICO) {
        #pragma unroll
        for (int r = 0; r < 4; ++r) {
          int row = mtile * 64 + wm * 32 + mt * 16 + quad * 4 + r;
          out[(size_t)row * NICO + i] = acc[mt][nt][r];
        }
      }
    }
}

// ---------------- k_xg: xg = x · icoB^T (inline fp32->bf16 staging) ----------------
__global__ __launch_bounds__(256) void k_xg(const float* __restrict__ x,
                                            const ushort* __restrict__ icoB,
                                            float* __restrict__ xg) {
  __shared__ __align__(16) short As[64 * 64];
  __shared__ __align__(16) short Bs[64 * 64];
  int mtile = blockIdx.x;
  int tid = threadIdx.x;
  int lane = tid & 63, wid = tid >> 6;
  int quad = lane >> 4, lr = lane & 15;
  int wm = wid >> 1, wn = wid & 1;
  f32x4 acc[2][2];
  #pragma unroll
  for (int a = 0; a < 2; ++a)
    #pragma unroll
    for (int b = 0; b < 2; ++b) acc[a][b] = (f32x4){0.f, 0.f, 0.f, 0.f};
  for (int kc = 0; kc < JP; kc += 64) {
    __syncthreads();
    #pragma unroll
    for (int it = 0; it < 2; ++it) {
      int s = it * 256 + tid;
      int r = s >> 3, p8 = s & 7, p = p8 ^ (r & 7);
      const float* xr = x + (size_t)(mtile * 64 + r) * GJ;
      int j0 = kc + p * 8;
      bf16x8 v8;
      #pragma unroll
      for (int jj = 0; jj < 8; ++jj) {
        int j = j0 + jj;
        v8[jj] = (j < GJ) ? (short)f2bf(xr[j]) : (short)0;
      }
      *(bf16x8*)&As[s * 8] = v8;
    }
    #pragma unroll
    for (int it = 0; it < 2; ++it) {
      int s0 = (wid * 2 + it) * 64;
      int s = s0 + lane;
      int r = s >> 3, p8 = s & 7, p = p8 ^ (r & 7);
      const ushort* gb = icoB + (size_t)r * JP + kc + p * 8;
      __builtin_amdgcn_global_load_lds(
          (const __attribute__((address_space(1))) u32*)gb,
          (__attribute__((address_space(3))) u32*)(Bs + s0 * 8), 16, 0, 0);
    }
    __syncthreads();
    #pragma unroll
    for (int ks = 0; ks < 2; ++ks) {
      int v = (ks * 4 + quad) ^ (lr & 7);
      bf16x8 af[2], bfv[2];
      #pragma unroll
      for (int mt = 0; mt < 2; ++mt)
        af[mt] = *(const bf16x8*)&As[(wm * 32 + mt * 16 + lr) * 64 + v * 8];
      #pragma unroll
      for (int nt = 0; nt < 2; ++nt)
        bfv[nt] = *(const bf16x8*)&Bs[(wn * 32 + nt * 16 + lr) * 64 + v * 8];
      #pragma unroll
      for (int mt = 0; mt < 2; ++mt)
        #pragma unroll
        for (int nt = 0; nt < 2; ++nt)
          acc[mt][nt] = __builtin_amdgcn_mfma_f32_16x16x32_bf16(af[mt], bfv[nt], acc[mt][nt], 0, 0, 0);
    }
  }
  #pragma unroll
  for (int mt = 0; mt < 2; ++mt)
    #pragma unroll
    for (int nt = 0; nt < 2; ++nt) {
      int i = wn * 32 + nt * 16 + lr;
      if (i < NICO) {
        #pragma unroll
        for (int r = 0; r < 4; ++r) {
          int row = mtile * 64 + wm * 32 + mt * 16 + quad * 4 + r;
          xg[(size_t)row * NICO + i] = acc[mt][nt][r];
        }
      }
    }
}

extern "C" void kernel_launch(void* const* d_in, const int* in_sizes, int n_in,
                              void* d_out, int out_size, void* d_ws, size_t ws_size,
                              hipStream_t stream) {
  const float *x = nullptr, *traj = nullptr, *w1s = nullptr, *w1v = nullptr;
  const float *Din = nullptr, *Dout = nullptr, *ico = nullptr;
  W7 w2{};
  for (int i = 0; i < n_in; ++i) {
    const float* p = (const float*)d_in[i];
    switch (in_sizes[i]) {
      case 7454720: x = p; break;
      case 5120:    traj = p; break;
      case 16:      w1s = p; break;
      case 144:     w1v = p; break;
      case 40960:   Din = p; break;
      case 1863680: Dout = p; break;
      case 27300:   ico = p; break;
      case 1024:    w2.p[0] = p; break;
      case 9216:    w2.p[1] = p; break;
      case 25600:   w2.p[2] = p; break;
      case 50176:   w2.p[3] = p; break;
      case 82944:   w2.p[4] = p; break;
      case 123904:  w2.p[5] = p; break;
      case 173056:  w2.p[6] = p; break;
      default: break;
    }
  }
  // ws layout (bytes, all 16B aligned): total ~55.9 MB
  char* wsb = (char*)d_ws;
  float*  h       = (float*)wsb;                       //    327,680 B
  ushort* h2b     = (ushort*)(wsb + 327680);           //  7,454,720 B
  ushort* DoutBT  = (ushort*)(wsb + 7782400);          //  4,194,304 B
  ushort* icoB    = (ushort*)(wsb + 11976704);         //     65,536 B
  ushort* Abuf    = (ushort*)(wsb + 12042240);         //  9,175,040 B
  ushort* Bbuf    = (ushort*)(wsb + 21217280);         //  1,146,880 B
  ushort* trajbf  = (ushort*)(wsb + 22364160);         // 33,554,432 B
  float* xg    = (float*)d_out;
  float* trajo = (float*)d_out + 983040;

  k_h    <<<dim3(320),    dim3(256), 0, stream>>>(traj, w1s, w1v, h);
  k_icoB <<<dim3(128),    dim3(256), 0, stream>>>(ico, icoB);
  k_bt   <<<dim3(8, 64),  dim3(256), 0, stream>>>(Dout, DoutBT);
  k_mm   <<<dim3(4, 128), dim3(256), 0, stream>>>(h, Din, DoutBT, h2b);
  k_hT   <<<dim3(512),    dim3(256), 0, stream>>>(h2b, Abuf);
  k_wT   <<<dim3(2240),   dim3(256), 0, stream>>>(w2, Bbuf);
  k_batch<<<dim3(3640),   dim3(256), 0, stream>>>(Abuf, Bbuf, trajbf);
  k_gt   <<<dim3(512),    dim3(256), 0, stream>>>(trajbf, icoB, trajo);
  k_xg   <<<dim3(256),    dim3(256), 0, stream>>>(x, icoB, xg);
}

// Round 4
// 318.016 us; speedup vs baseline: 4.4279x; 1.2700x over previous
//
#include <hip/hip_runtime.h>
#include <math.h>

// EquiGroupSamplingIco — round 4: k_mm split into k_sig (sig->global, computed once)
// + k_mm2 (pure bf16 MFMA GEMM, double-buffered LDS, one barrier/iter).
// sigb (33.5 MB/half) aliases the trajbf region; M split in 2 halves so ws stays
// at the R3-proven 55.9 MB. Tail kernels unchanged except k_hT load vectorization.

#define NBT  512
#define F8c  16
#define F2c  64
#define GJ   455
#define GG   4096
#define NICO 60
#define JP   512      // padded j for trajbf / icoB

typedef short bf16x8 __attribute__((ext_vector_type(8)));
typedef float f32x4  __attribute__((ext_vector_type(4)));
typedef unsigned int u32;
typedef unsigned short ushort;

struct W7 { const float* p[7]; };

__device__ __forceinline__ ushort f2bf(float f) {
  u32 u = __float_as_uint(f);
  return (ushort)((u + 0x7fffu + ((u >> 16) & 1u)) >> 16);   // RNE
}

__device__ __forceinline__ int sel7(int l, int a0, int a1, int a2, int a3,
                                    int a4, int a5, int a6) {
  int r = a6;
  r = (l == 5) ? a5 : r; r = (l == 4) ? a4 : r; r = (l == 3) ? a3 : r;
  r = (l == 2) ? a2 : r; r = (l == 1) ? a1 : r; r = (l == 0) ? a0 : r;
  return r;
}

// ---------------- k_h ----------------
__global__ __launch_bounds__(256) void k_h(const float* __restrict__ traj,
                                           const float* __restrict__ w1s,
                                           const float* __restrict__ w1v,
                                           float* __restrict__ h) {
  int idx = blockIdx.x * 256 + threadIdx.x;
  if (idx >= NBT * 160) return;
  int bt = idx / 160, r = idx % 160, c = r / 10, i = r % 10;
  const float* tr = traj + bt * 10;
  float val;
  if (i == 0) {
    val = tr[9] * w1s[c];
  } else {
    int k = i - 1, v = k / 3, m = k % 3;
    float s = 0.f;
    #pragma unroll
    for (int u = 0; u < 3; ++u) s = fmaf(tr[u * 3 + m], w1v[c * 9 + u * 3 + v], s);
    val = s * 0.57735026918962576f;
  }
  h[idx] = val;
}

// ---------------- k_icoB: icoB[i][j] bf16, 64x512 zero-padded ----------------
__global__ __launch_bounds__(256) void k_icoB(const float* __restrict__ ico,
                                              ushort* __restrict__ icoB) {
  int e = blockIdx.x * 256 + threadIdx.x;   // 32768
  int i = e >> 9, j = e & 511;
  icoB[e] = (i < NICO && j < GJ) ? f2bf(ico[i * GJ + j]) : (ushort)0;
}

// ---------------- k_bt: DoutBT[j][k] bf16, j padded to 512 ----------------
__global__ __launch_bounds__(256) void k_bt(const float* __restrict__ Dout,
                                            ushort* __restrict__ DoutBT) {
  __shared__ float t[64][65];
  int jt = blockIdx.x, kt = blockIdx.y;
  int tx = threadIdx.x & 63, ty = threadIdx.x >> 6;
  #pragma unroll
  for (int i = 0; i < 16; ++i) {
    int r = i * 4 + ty, j = jt * 64 + tx;
    t[r][tx] = (j < GJ) ? Dout[(size_t)(kt * 64 + r) * GJ + j] : 0.f;
  }
  __syncthreads();
  #pragma unroll
  for (int i = 0; i < 16; ++i) {
    int jl = i * 4 + ty;
    DoutBT[(size_t)(jt * 64 + jl) * GG + kt * 64 + tx] = f2bf(t[tx][jl]);
  }
}

// ---------------- k_sig: sigb[m][k] = bf16(relu(h[m]·Din[k])), one M-half ----------------
// block: 16 rows x 2048 k. Thread owns k-chunk of 8 (Din rows in 80 registers,
// coalesced float4 loads), loops 16 rows (h broadcast from LDS). Stores bf16x8.
__global__ __launch_bounds__(256) void k_sig(const float* __restrict__ h,      // half base
                                             const float* __restrict__ Din,
                                             ushort* __restrict__ sigb) {      // [4096][4096]
  __shared__ float hs[160];
  int tid = threadIdx.x;
  int mb = blockIdx.y;           // 0..255
  int kt = blockIdx.x;           // 0..1
  if (tid < 160) hs[tid] = h[mb * 160 + tid];
  float dr[80];
  const float4* dp = (const float4*)(Din + (size_t)(kt * 2048 + tid * 8) * 10);
  #pragma unroll
  for (int q = 0; q < 20; ++q) {
    float4 v = dp[q];
    dr[q * 4 + 0] = v.x; dr[q * 4 + 1] = v.y; dr[q * 4 + 2] = v.z; dr[q * 4 + 3] = v.w;
  }
  __syncthreads();
  #pragma unroll
  for (int r = 0; r < 16; ++r) {
    float hv[10];
    #pragma unroll
    for (int i = 0; i < 10; ++i) hv[i] = hs[r * 10 + i];
    bf16x8 o;
    #pragma unroll
    for (int j = 0; j < 8; ++j) {
      float s = 0.f;
      #pragma unroll
      for (int i = 0; i < 10; ++i) s = fmaf(hv[i], dr[j * 10 + i], s);
      o[j] = (short)f2bf(fmaxf(s, 0.f));
    }
    *(bf16x8*)&sigb[((size_t)(mb * 16 + r)) * GG + kt * 2048 + tid * 8] = o;
  }
}

// ---------------- k_mm2: C[m][j] = sigb · DoutBT^T, one M-half ----------------
// 64x128 tile, BK=64, 4 waves (2x2; wave tile 32x64), dbuf LDS, 1 barrier/iter.
__global__ __launch_bounds__(256) void k_mm2(const ushort* __restrict__ A,     // [4096][4096]
                                             const ushort* __restrict__ Bm,    // [512][4096]
                                             ushort* __restrict__ C) {         // [4096][455]
  __shared__ __align__(16) short Asb[2][64 * 64];    // 2 x 8 KB
  __shared__ __align__(16) short Bsb[2][128 * 64];   // 2 x 16 KB
  int tid = threadIdx.x;
  int lane = tid & 63, wid = tid >> 6;
  int quad = lane >> 4, lr = lane & 15;
  int wm = wid >> 1, wn = wid & 1;
  int nb = blockIdx.x, mb = blockIdx.y;

  f32x4 acc[2][4];
  #pragma unroll
  for (int a = 0; a < 2; ++a)
    #pragma unroll
    for (int b = 0; b < 4; ++b) acc[a][b] = (f32x4){0.f, 0.f, 0.f, 0.f};

  const ushort* Ab = A + (size_t)mb * 64 * GG;
  const ushort* Bb = Bm + (size_t)nb * 128 * GG;

  auto stage = [&](int buf, int kc) {
    #pragma unroll
    for (int it = 0; it < 2; ++it) {                 // A: 512 slots / 4 waves
      int s0 = (wid * 2 + it) * 64;
      int s = s0 + lane;
      int r = s >> 3, pp = s & 7, p = pp ^ (r & 7);
      __builtin_amdgcn_global_load_lds(
          (const __attribute__((address_space(1))) u32*)(Ab + (size_t)r * GG + kc + p * 8),
          (__attribute__((address_space(3))) u32*)(&Asb[buf][s0 * 8]), 16, 0, 0);
    }
    #pragma unroll
    for (int it = 0; it < 4; ++it) {                 // B: 1024 slots / 4 waves
      int s0 = (wid * 4 + it) * 64;
      int s = s0 + lane;
      int r = s >> 3, pp = s & 7, p = pp ^ (r & 7);
      __builtin_amdgcn_global_load_lds(
          (const __attribute__((address_space(1))) u32*)(Bb + (size_t)r * GG + kc + p * 8),
          (__attribute__((address_space(3))) u32*)(&Bsb[buf][s0 * 8]), 16, 0, 0);
    }
  };

  stage(0, 0);
  __syncthreads();
  for (int it = 0; it < 64; ++it) {
    int cur = it & 1;
    if (it < 63) stage(cur ^ 1, (it + 1) * 64);      // in flight during compute
    #pragma unroll
    for (int ks = 0; ks < 2; ++ks) {
      bf16x8 af[2], bv[4];
      #pragma unroll
      for (int mt = 0; mt < 2; ++mt) {
        int ra = wm * 32 + mt * 16 + lr;
        int v = (ks * 4 + quad) ^ (ra & 7);
        af[mt] = *(const bf16x8*)&Asb[cur][(ra * 8 + v) * 8];
      }
      #pragma unroll
      for (int nt = 0; nt < 4; ++nt) {
        int rb = wn * 64 + nt * 16 + lr;
        int v = (ks * 4 + quad) ^ (rb & 7);
        bv[nt] = *(const bf16x8*)&Bsb[cur][(rb * 8 + v) * 8];
      }
      #pragma unroll
      for (int mt = 0; mt < 2; ++mt)
        #pragma unroll
        for (int nt = 0; nt < 4; ++nt)
          acc[mt][nt] = __builtin_amdgcn_mfma_f32_16x16x32_bf16(af[mt], bv[nt], acc[mt][nt], 0, 0, 0);
    }
    __syncthreads();                                 // drains prefetch; protects dbuf swap
  }
  #pragma unroll
  for (int mt = 0; mt < 2; ++mt)
    #pragma unroll
    for (int nt = 0; nt < 4; ++nt) {
      int j = nb * 128 + wn * 64 + nt * 16 + lr;
      if (j < GJ) {
        #pragma unroll
        for (int r = 0; r < 4; ++r) {
          int m = mb * 64 + wm * 32 + mt * 16 + quad * 4 + r;
          C[(size_t)m * GJ + j] = f2bf(acc[mt][nt][r]);
        }
      }
    }
}

// per-l constants
// d:  1,3,5,7,9,11,13   Kp: 64,64,128,128,192,192,256   o: 0,1,10,35,84,165,286
// Aoff(el): 0,32768,131072,458752,917504,1802240,2883584
// Boff(el): 0,4096,16384,57344,114688,225280,360448
// blocks cum: 8,80,280,672,1320,2288,3640

// ---------------- k_hT: h2b -> per-l A operand layout ----------------
__global__ __launch_bounds__(256) void k_hT(const ushort* __restrict__ h2b,
                                            ushort* __restrict__ Abuf) {
  __shared__ __align__(16) ushort hsl[7280];
  int bt = blockIdx.x, tid = threadIdx.x;
  const uint4* src = (const uint4*)(h2b + (size_t)bt * 7280);
  for (int e = tid; e < 910; e += 256) ((uint4*)hsl)[e] = src[e];
  __syncthreads();
  for (int e = tid; e < 8960; e += 256) {
    int l = (e >= 64) + (e >= 256) + (e >= 896) + (e >= 1792) + (e >= 3520) + (e >= 5632);
    int base = sel7(l, 0, 64, 256, 896, 1792, 3520, 5632);
    int d    = sel7(l, 1, 3, 5, 7, 9, 11, 13);
    int Kp   = sel7(l, 64, 64, 128, 128, 192, 192, 256);
    int o    = sel7(l, 0, 1, 10, 35, 84, 165, 286);
    int Aoff = sel7(l, 0, 32768, 131072, 458752, 917504, 1802240, 2883584);
    int local = e - base;
    int m = local / Kp, kcol = local - m * Kp;
    ushort val = 0;
    if (kcol < 16 * d) {
      int f = kcol / d, u = kcol - f * d;
      val = hsl[f * GJ + o + u * d + m];
    }
    Abuf[(size_t)Aoff + ((size_t)bt * d + m) * Kp + kcol] = val;
  }
}

// ---------------- k_wT: w2 -> per-l B operand layout (scale folded) ----------------
__global__ __launch_bounds__(256) void k_wT(W7 w2, ushort* __restrict__ Bbuf) {
  int ee = blockIdx.x * 256 + threadIdx.x;
  if (ee >= 573440) return;
  int l = (ee >= 4096) + (ee >= 16384) + (ee >= 57344) + (ee >= 114688) +
          (ee >= 225280) + (ee >= 360448);
  int base = sel7(l, 0, 4096, 16384, 57344, 114688, 225280, 360448);
  int d    = sel7(l, 1, 3, 5, 7, 9, 11, 13);
  int Kp   = sel7(l, 64, 64, 128, 128, 192, 192, 256);
  int local = ee - base;
  int row = local / Kp, kcol = local - row * Kp;
  int g2 = row / d, v = row - g2 * d;
  ushort val = 0;
  if (kcol < 16 * d) {
    int f = kcol / d, u = kcol - f * d;
    const float* wl = w2.p[l];
    float scl = rsqrtf(16.f * (float)d);
    val = f2bf(wl[(((size_t)f * 64 + g2) * d + u) * d + v] * scl);
  }
  Bbuf[ee] = val;
}

// ---------------- k_batch: 7 per-l GEMMs, scatter into trajbf ----------------
__global__ __launch_bounds__(256) void k_batch(const ushort* __restrict__ Abuf,
                                               const ushort* __restrict__ Bbuf,
                                               ushort* __restrict__ trajbf) {
  __shared__ __align__(16) short As[64 * 64];
  __shared__ __align__(16) short Bs[64 * 64];
  int bid = blockIdx.x;
  int l = (bid >= 8) + (bid >= 80) + (bid >= 280) + (bid >= 672) +
          (bid >= 1320) + (bid >= 2288);
  int bbase = sel7(l, 0, 8, 80, 280, 672, 1320, 2288);
  int d     = sel7(l, 1, 3, 5, 7, 9, 11, 13);
  int Kp    = sel7(l, 64, 64, 128, 128, 192, 192, 256);
  int o     = sel7(l, 0, 1, 10, 35, 84, 165, 286);
  int Aoff  = sel7(l, 0, 32768, 131072, 458752, 917504, 1802240, 2883584);
  int Boff  = sel7(l, 0, 4096, 16384, 57344, 114688, 225280, 360448);
  int t = bid - bbase;
  int mtile = t / d, ntile = t - mtile * d;

  int tid = threadIdx.x;
  int lane = tid & 63, wid = tid >> 6;
  int quad = lane >> 4, lr = lane & 15;
  int wm = wid >> 1, wn = wid & 1;

  f32x4 acc[2][2];
  #pragma unroll
  for (int a = 0; a < 2; ++a)
    #pragma unroll
    for (int b = 0; b < 2; ++b) acc[a][b] = (f32x4){0.f, 0.f, 0.f, 0.f};

  const ushort* Ab = Abuf + Aoff;
  const ushort* Bb = Bbuf + Boff;

  for (int kc = 0; kc < Kp; kc += 64) {
    __syncthreads();
    #pragma unroll
    for (int it = 0; it < 2; ++it) {
      int s0 = (wid * 2 + it) * 64;
      int s = s0 + lane;
      int r = s >> 3, p8 = s & 7, p = p8 ^ (r & 7);
      const ushort* ga = Ab + (size_t)(mtile * 64 + r) * Kp + kc + p * 8;
      __builtin_amdgcn_global_load_lds(
          (const __attribute__((address_space(1))) u32*)ga,
          (__attribute__((address_space(3))) u32*)(As + s0 * 8), 16, 0, 0);
      const ushort* gb = Bb + (size_t)(ntile * 64 + r) * Kp + kc + p * 8;
      __builtin_amdgcn_global_load_lds(
          (const __attribute__((address_space(1))) u32*)gb,
          (__attribute__((address_space(3))) u32*)(Bs + s0 * 8), 16, 0, 0);
    }
    __syncthreads();
    #pragma unroll
    for (int ks = 0; ks < 2; ++ks) {
      int v = (ks * 4 + quad) ^ (lr & 7);
      bf16x8 af[2], bfv[2];
      #pragma unroll
      for (int mt = 0; mt < 2; ++mt)
        af[mt] = *(const bf16x8*)&As[(wm * 32 + mt * 16 + lr) * 64 + v * 8];
      #pragma unroll
      for (int nt = 0; nt < 2; ++nt)
        bfv[nt] = *(const bf16x8*)&Bs[(wn * 32 + nt * 16 + lr) * 64 + v * 8];
      #pragma unroll
      for (int mt = 0; mt < 2; ++mt)
        #pragma unroll
        for (int nt = 0; nt < 2; ++nt)
          acc[mt][nt] = __builtin_amdgcn_mfma_f32_16x16x32_bf16(af[mt], bfv[nt], acc[mt][nt], 0, 0, 0);
    }
  }
  #pragma unroll
  for (int mt = 0; mt < 2; ++mt)
    #pragma unroll
    for (int nt = 0; nt < 2; ++nt)
      #pragma unroll
      for (int r = 0; r < 4; ++r) {
        int Mrow = mtile * 64 + wm * 32 + mt * 16 + quad * 4 + r;
        int Ncol = ntile * 64 + wn * 32 + nt * 16 + lr;
        int bt = Mrow / d, m = Mrow - bt * d;
        int g2 = Ncol / d, v = Ncol - g2 * d;
        trajbf[(size_t)(bt * 64 + g2) * JP + o + v * d + m] = f2bf(acc[mt][nt][r]);
      }
}

// ---------------- k_gt: trajo = trajbf · icoB^T ----------------
__global__ __launch_bounds__(256) void k_gt(const ushort* __restrict__ trajbf,
                                            const ushort* __restrict__ icoB,
                                            float* __restrict__ out) {
  __shared__ __align__(16) short As[64 * 64];
  __shared__ __align__(16) short Bs[64 * 64];
  int mtile = blockIdx.x;
  int tid = threadIdx.x;
  int lane = tid & 63, wid = tid >> 6;
  int quad = lane >> 4, lr = lane & 15;
  int wm = wid >> 1, wn = wid & 1;
  f32x4 acc[2][2];
  #pragma unroll
  for (int a = 0; a < 2; ++a)
    #pragma unroll
    for (int b = 0; b < 2; ++b) acc[a][b] = (f32x4){0.f, 0.f, 0.f, 0.f};
  for (int kc = 0; kc < JP; kc += 64) {
    __syncthreads();
    #pragma unroll
    for (int it = 0; it < 2; ++it) {
      int s0 = (wid * 2 + it) * 64;
      int s = s0 + lane;
      int r = s >> 3, p8 = s & 7, p = p8 ^ (r & 7);
      const ushort* ga = trajbf + (size_t)(mtile * 64 + r) * JP + kc + p * 8;
      __builtin_amdgcn_global_load_lds(
          (const __attribute__((address_space(1))) u32*)ga,
          (__attribute__((address_space(3))) u32*)(As + s0 * 8), 16, 0, 0);
      const ushort* gb = icoB + (size_t)r * JP + kc + p * 8;
      __builtin_amdgcn_global_load_lds(
          (const __attribute__((address_space(1))) u32*)gb,
          (__attribute__((address_space(3))) u32*)(Bs + s0 * 8), 16, 0, 0);
    }
    __syncthreads();
    #pragma unroll
    for (int ks = 0; ks < 2; ++ks) {
      int v = (ks * 4 + quad) ^ (lr & 7);
      bf16x8 af[2], bfv[2];
      #pragma unroll
      for (int mt = 0; mt < 2; ++mt)
        af[mt] = *(const bf16x8*)&As[(wm * 32 + mt * 16 + lr) * 64 + v * 8];
      #pragma unroll
      for (int nt = 0; nt < 2; ++nt)
        bfv[nt] = *(const bf16x8*)&Bs[(wn * 32 + nt * 16 + lr) * 64 + v * 8];
      #pragma unroll
      for (int mt = 0; mt < 2; ++mt)
        #pragma unroll
        for (int nt = 0; nt < 2; ++nt)
          acc[mt][nt] = __builtin_amdgcn_mfma_f32_16x16x32_bf16(af[mt], bfv[nt], acc[mt][nt], 0, 0, 0);
    }
  }
  #pragma unroll
  for (int mt = 0; mt < 2; ++mt)
    #pragma unroll
    for (int nt = 0; nt < 2; ++nt) {
      int i = wn * 32 + nt * 16 + lr;
      if (i < NICO) {
        #pragma unroll
        for (int r = 0; r < 4; ++r) {
          int row = mtile * 64 + wm * 32 + mt * 16 + quad * 4 + r;
          out[(size_t)row * NICO + i] = acc[mt][nt][r];
        }
      }
    }
}

// ---------------- k_xg: xg = x · icoB^T (inline fp32->bf16 staging) ----------------
__global__ __launch_bounds__(256) void k_xg(const float* __restrict__ x,
                                            const ushort* __restrict__ icoB,
                                            float* __restrict__ xg) {
  __shared__ __align__(16) short As[64 * 64];
  __shared__ __align__(16) short Bs[64 * 64];
  int mtile = blockIdx.x;
  int tid = threadIdx.x;
  int lane = tid & 63, wid = tid >> 6;
  int quad = lane >> 4, lr = lane & 15;
  int wm = wid >> 1, wn = wid & 1;
  f32x4 acc[2][2];
  #pragma unroll
  for (int a = 0; a < 2; ++a)
    #pragma unroll
    for (int b = 0; b < 2; ++b) acc[a][b] = (f32x4){0.f, 0.f, 0.f, 0.f};
  for (int kc = 0; kc < JP; kc += 64) {
    __syncthreads();
    #pragma unroll
    for (int it = 0; it < 2; ++it) {
      int s = it * 256 + tid;
      int r = s >> 3, p8 = s & 7, p = p8 ^ (r & 7);
      const float* xr = x + (size_t)(mtile * 64 + r) * GJ;
      int j0 = kc + p * 8;
      bf16x8 v8;
      #pragma unroll
      for (int jj = 0; jj < 8; ++jj) {
        int j = j0 + jj;
        v8[jj] = (j < GJ) ? (short)f2bf(xr[j]) : (short)0;
      }
      *(bf16x8*)&As[s * 8] = v8;
    }
    #pragma unroll
    for (int it = 0; it < 2; ++it) {
      int s0 = (wid * 2 + it) * 64;
      int s = s0 + lane;
      int r = s >> 3, p8 = s & 7, p = p8 ^ (r & 7);
      const ushort* gb = icoB + (size_t)r * JP + kc + p * 8;
      __builtin_amdgcn_global_load_lds(
          (const __attribute__((address_space(1))) u32*)gb,
          (__attribute__((address_space(3))) u32*)(Bs + s0 * 8), 16, 0, 0);
    }
    __syncthreads();
    #pragma unroll
    for (int ks = 0; ks < 2; ++ks) {
      int v = (ks * 4 + quad) ^ (lr & 7);
      bf16x8 af[2], bfv[2];
      #pragma unroll
      for (int mt = 0; mt < 2; ++mt)
        af[mt] = *(const bf16x8*)&As[(wm * 32 + mt * 16 + lr) * 64 + v * 8];
      #pragma unroll
      for (int nt = 0; nt < 2; ++nt)
        bfv[nt] = *(const bf16x8*)&Bs[(wn * 32 + nt * 16 + lr) * 64 + v * 8];
      #pragma unroll
      for (int mt = 0; mt < 2; ++mt)
        #pragma unroll
        for (int nt = 0; nt < 2; ++nt)
          acc[mt][nt] = __builtin_amdgcn_mfma_f32_16x16x32_bf16(af[mt], bfv[nt], acc[mt][nt], 0, 0, 0);
    }
  }
  #pragma unroll
  for (int mt = 0; mt < 2; ++mt)
    #pragma unroll
    for (int nt = 0; nt < 2; ++nt) {
      int i = wn * 32 + nt * 16 + lr;
      if (i < NICO) {
        #pragma unroll
        for (int r = 0; r < 4; ++r) {
          int row = mtile * 64 + wm * 32 + mt * 16 + quad * 4 + r;
          xg[(size_t)row * NICO + i] = acc[mt][nt][r];
        }
      }
    }
}

extern "C" void kernel_launch(void* const* d_in, const int* in_sizes, int n_in,
                              void* d_out, int out_size, void* d_ws, size_t ws_size,
                              hipStream_t stream) {
  const float *x = nullptr, *traj = nullptr, *w1s = nullptr, *w1v = nullptr;
  const float *Din = nullptr, *Dout = nullptr, *ico = nullptr;
  W7 w2{};
  for (int i = 0; i < n_in; ++i) {
    const float* p = (const float*)d_in[i];
    switch (in_sizes[i]) {
      case 7454720: x = p; break;
      case 5120:    traj = p; break;
      case 16:      w1s = p; break;
      case 144:     w1v = p; break;
      case 40960:   Din = p; break;
      case 1863680: Dout = p; break;
      case 27300:   ico = p; break;
      case 1024:    w2.p[0] = p; break;
      case 9216:    w2.p[1] = p; break;
      case 25600:   w2.p[2] = p; break;
      case 50176:   w2.p[3] = p; break;
      case 82944:   w2.p[4] = p; break;
      case 123904:  w2.p[5] = p; break;
      case 173056:  w2.p[6] = p; break;
      default: break;
    }
  }
  // ws layout (bytes): total ~55.9 MB (same as R3).
  // trajbf region (33,554,432 B) doubles as sigb (4096*4096*2 B — identical size):
  // k_sig/k_mm2 halves run before k_batch writes trajbf.
  char* wsb = (char*)d_ws;
  float*  h       = (float*)wsb;                       //    327,680 B
  ushort* h2b     = (ushort*)(wsb + 327680);           //  7,454,720 B
  ushort* DoutBT  = (ushort*)(wsb + 7782400);          //  4,194,304 B
  ushort* icoB    = (ushort*)(wsb + 11976704);         //     65,536 B
  ushort* Abuf    = (ushort*)(wsb + 12042240);         //  9,175,040 B
  ushort* Bbuf    = (ushort*)(wsb + 21217280);         //  1,146,880 B
  ushort* trajbf  = (ushort*)(wsb + 22364160);         // 33,554,432 B
  ushort* sigb    = trajbf;                            // alias (see above)
  float* xg    = (float*)d_out;
  float* trajo = (float*)d_out + 983040;

  k_h    <<<dim3(320),    dim3(256), 0, stream>>>(traj, w1s, w1v, h);
  k_icoB <<<dim3(128),    dim3(256), 0, stream>>>(ico, icoB);
  k_bt   <<<dim3(8, 64),  dim3(256), 0, stream>>>(Dout, DoutBT);
  for (int half = 0; half < 2; ++half) {
    k_sig <<<dim3(2, 256), dim3(256), 0, stream>>>(h + (size_t)half * 40960, Din, sigb);
    k_mm2 <<<dim3(4, 64),  dim3(256), 0, stream>>>(sigb, DoutBT, h2b + (size_t)half * 4096 * GJ);
  }
  k_hT   <<<dim3(512),    dim3(256), 0, stream>>>(h2b, Abuf);
  k_wT   <<<dim3(2240),   dim3(256), 0, stream>>>(w2, Bbuf);
  k_batch<<<dim3(3640),   dim3(256), 0, stream>>>(Abuf, Bbuf, trajbf);
  k_gt   <<<dim3(512),    dim3(256), 0, stream>>>(trajbf, icoB, trajo);
  k_xg   <<<dim3(256),    dim3(256), 0, stream>>>(x, icoB, xg);
}

// Round 5
// 281.466 us; speedup vs baseline: 5.0029x; 1.1299x over previous
//
#include <hip/hip_runtime.h>
#include <math.h>

// EquiGroupSamplingIco — round 5:
//  - k_mm2: NT=64 -> 512 blocks/half (2 blocks/CU; TLP hides the barrier drain),
//           epilogue scatters bf16 DIRECTLY into Abuf (k_hT + h2b eliminated).
//  - Abuf pad zones zeroed once per call via hipMemsetAsync.
//  - k_gt+k_xg merged into k_ico (768 blocks); k_h+k_icoB merged into k_hic.

#define NBT  512
#define F8c  16
#define F2c  64
#define GJ   455
#define GG   4096
#define NICO 60
#define JP   512      // padded j for trajbf / icoB

typedef short bf16x8 __attribute__((ext_vector_type(8)));
typedef float f32x4  __attribute__((ext_vector_type(4)));
typedef unsigned int u32;
typedef unsigned short ushort;

struct W7 { const float* p[7]; };

__device__ __forceinline__ ushort f2bf(float f) {
  u32 u = __float_as_uint(f);
  return (ushort)((u + 0x7fffu + ((u >> 16) & 1u)) >> 16);   // RNE
}

__device__ __forceinline__ int sel7(int l, int a0, int a1, int a2, int a3,
                                    int a4, int a5, int a6) {
  int r = a6;
  r = (l == 5) ? a5 : r; r = (l == 4) ? a4 : r; r = (l == 3) ? a3 : r;
  r = (l == 2) ? a2 : r; r = (l == 1) ? a1 : r; r = (l == 0) ? a0 : r;
  return r;
}

// ---------------- k_hic: k_h (blocks 0..319) + icoB build (blocks 320..447) ----------------
__global__ __launch_bounds__(256) void k_hic(const float* __restrict__ traj,
                                             const float* __restrict__ w1s,
                                             const float* __restrict__ w1v,
                                             const float* __restrict__ ico,
                                             float* __restrict__ h,
                                             ushort* __restrict__ icoB) {
  if (blockIdx.x < 320) {
    int idx = blockIdx.x * 256 + threadIdx.x;
    if (idx >= NBT * 160) return;
    int bt = idx / 160, r = idx % 160, c = r / 10, i = r % 10;
    const float* tr = traj + bt * 10;
    float val;
    if (i == 0) {
      val = tr[9] * w1s[c];
    } else {
      int k = i - 1, v = k / 3, m = k % 3;
      float s = 0.f;
      #pragma unroll
      for (int u = 0; u < 3; ++u) s = fmaf(tr[u * 3 + m], w1v[c * 9 + u * 3 + v], s);
      val = s * 0.57735026918962576f;
    }
    h[idx] = val;
  } else {
    int e = (blockIdx.x - 320) * 256 + threadIdx.x;   // 32768
    int i = e >> 9, j = e & 511;
    icoB[e] = (i < NICO && j < GJ) ? f2bf(ico[i * GJ + j]) : (ushort)0;
  }
}

// ---------------- k_bt: DoutBT[j][k] bf16, j padded to 512 ----------------
__global__ __launch_bounds__(256) void k_bt(const float* __restrict__ Dout,
                                            ushort* __restrict__ DoutBT) {
  __shared__ float t[64][65];
  int jt = blockIdx.x, kt = blockIdx.y;
  int tx = threadIdx.x & 63, ty = threadIdx.x >> 6;
  #pragma unroll
  for (int i = 0; i < 16; ++i) {
    int r = i * 4 + ty, j = jt * 64 + tx;
    t[r][tx] = (j < GJ) ? Dout[(size_t)(kt * 64 + r) * GJ + j] : 0.f;
  }
  __syncthreads();
  #pragma unroll
  for (int i = 0; i < 16; ++i) {
    int jl = i * 4 + ty;
    DoutBT[(size_t)(jt * 64 + jl) * GG + kt * 64 + tx] = f2bf(t[tx][jl]);
  }
}

// ---------------- k_sig: sigb[m][k] = bf16(relu(h[m]·Din[k])), one M-half ----------------
__global__ __launch_bounds__(256) void k_sig(const float* __restrict__ h,      // half base
                                             const float* __restrict__ Din,
                                             ushort* __restrict__ sigb) {      // [4096][4096]
  __shared__ float hs[160];
  int tid = threadIdx.x;
  int mb = blockIdx.y;           // 0..255
  int kt = blockIdx.x;           // 0..1
  if (tid < 160) hs[tid] = h[mb * 160 + tid];
  float dr[80];
  const float4* dp = (const float4*)(Din + (size_t)(kt * 2048 + tid * 8) * 10);
  #pragma unroll
  for (int q = 0; q < 20; ++q) {
    float4 v = dp[q];
    dr[q * 4 + 0] = v.x; dr[q * 4 + 1] = v.y; dr[q * 4 + 2] = v.z; dr[q * 4 + 3] = v.w;
  }
  __syncthreads();
  #pragma unroll
  for (int r = 0; r < 16; ++r) {
    float hv[10];
    #pragma unroll
    for (int i = 0; i < 10; ++i) hv[i] = hs[r * 10 + i];
    bf16x8 o;
    #pragma unroll
    for (int j = 0; j < 8; ++j) {
      float s = 0.f;
      #pragma unroll
      for (int i = 0; i < 10; ++i) s = fmaf(hv[i], dr[j * 10 + i], s);
      o[j] = (short)f2bf(fmaxf(s, 0.f));
    }
    *(bf16x8*)&sigb[((size_t)(mb * 16 + r)) * GG + kt * 2048 + tid * 8] = o;
  }
}

// ---------------- k_mm2: (sigb · DoutBT^T) scattered into Abuf, one M-half ----------------
// 64x64 tile, BK=64, 4 waves (2x2, wave tile 32x32), dbuf LDS, grid (8,64)=512 blocks.
__global__ __launch_bounds__(256) void k_mm2(const ushort* __restrict__ A,     // [4096][4096]
                                             const ushort* __restrict__ Bm,    // [512][4096]
                                             ushort* __restrict__ Abuf,
                                             int btBase) {
  __shared__ __align__(16) short Asb[2][64 * 64];    // 2 x 8 KB
  __shared__ __align__(16) short Bsb[2][64 * 64];    // 2 x 8 KB
  int tid = threadIdx.x;
  int lane = tid & 63, wid = tid >> 6;
  int quad = lane >> 4, lr = lane & 15;
  int wm = wid >> 1, wn = wid & 1;
  int nb = blockIdx.x, mb = blockIdx.y;

  f32x4 acc[2][2];
  #pragma unroll
  for (int a = 0; a < 2; ++a)
    #pragma unroll
    for (int b = 0; b < 2; ++b) acc[a][b] = (f32x4){0.f, 0.f, 0.f, 0.f};

  const ushort* Ab = A + (size_t)mb * 64 * GG;
  const ushort* Bb = Bm + (size_t)nb * 64 * GG;

  auto stage = [&](int buf, int kc) {
    #pragma unroll
    for (int it = 0; it < 2; ++it) {                 // A: 512 slots / 4 waves
      int s0 = (wid * 2 + it) * 64;
      int s = s0 + lane;
      int r = s >> 3, pp = s & 7, p = pp ^ (r & 7);
      __builtin_amdgcn_global_load_lds(
          (const __attribute__((address_space(1))) u32*)(Ab + (size_t)r * GG + kc + p * 8),
          (__attribute__((address_space(3))) u32*)(&Asb[buf][s0 * 8]), 16, 0, 0);
    }
    #pragma unroll
    for (int it = 0; it < 2; ++it) {                 // B: 512 slots / 4 waves
      int s0 = (wid * 2 + it) * 64;
      int s = s0 + lane;
      int r = s >> 3, pp = s & 7, p = pp ^ (r & 7);
      __builtin_amdgcn_global_load_lds(
          (const __attribute__((address_space(1))) u32*)(Bb + (size_t)r * GG + kc + p * 8),
          (__attribute__((address_space(3))) u32*)(&Bsb[buf][s0 * 8]), 16, 0, 0);
    }
  };

  stage(0, 0);
  __syncthreads();
  for (int it = 0; it < 64; ++it) {
    int cur = it & 1;
    if (it < 63) stage(cur ^ 1, (it + 1) * 64);
    #pragma unroll
    for (int ks = 0; ks < 2; ++ks) {
      bf16x8 af[2], bv[2];
      #pragma unroll
      for (int mt = 0; mt < 2; ++mt) {
        int ra = wm * 32 + mt * 16 + lr;
        int v = (ks * 4 + quad) ^ (ra & 7);
        af[mt] = *(const bf16x8*)&Asb[cur][(ra * 8 + v) * 8];
      }
      #pragma unroll
      for (int nt = 0; nt < 2; ++nt) {
        int rb = wn * 32 + nt * 16 + lr;
        int v = (ks * 4 + quad) ^ (rb & 7);
        bv[nt] = *(const bf16x8*)&Bsb[cur][(rb * 8 + v) * 8];
      }
      #pragma unroll
      for (int mt = 0; mt < 2; ++mt)
        #pragma unroll
        for (int nt = 0; nt < 2; ++nt)
          acc[mt][nt] = __builtin_amdgcn_mfma_f32_16x16x32_bf16(af[mt], bv[nt], acc[mt][nt], 0, 0, 0);
    }
    __syncthreads();
  }
  // epilogue: scatter bf16 directly into per-l A-operand layout (replaces k_hT)
  #pragma unroll
  for (int nt = 0; nt < 2; ++nt) {
    int j = nb * 64 + wn * 32 + nt * 16 + lr;
    if (j < GJ) {
      int l = (j >= 1) + (j >= 10) + (j >= 35) + (j >= 84) + (j >= 165) + (j >= 286);
      int o    = sel7(l, 0, 1, 10, 35, 84, 165, 286);
      int d    = sel7(l, 1, 3, 5, 7, 9, 11, 13);
      int Kp   = sel7(l, 64, 64, 128, 128, 192, 192, 256);
      int Aoff = sel7(l, 0, 32768, 131072, 458752, 917504, 1802240, 2883584);
      int jl = j - o;
      float rcpd = 1.0f / (float)d;
      int u = (int)(((float)jl + 0.5f) * rcpd);      // exact: margin 0.5/13 >> fp32 eps
      int mB = jl - u * d;
      #pragma unroll
      for (int mt = 0; mt < 2; ++mt)
        #pragma unroll
        for (int r = 0; r < 4; ++r) {
          int m = mb * 64 + wm * 32 + mt * 16 + quad * 4 + r;
          int btg = btBase + (m >> 4), f = m & 15;
          Abuf[(size_t)Aoff + ((size_t)btg * d + mB) * Kp + f * d + u] =
              f2bf(acc[mt][nt][r]);
        }
    }
  }
}

// per-l constants
// d:  1,3,5,7,9,11,13   Kp: 64,64,128,128,192,192,256   o: 0,1,10,35,84,165,286
// Aoff(el): 0,32768,131072,458752,917504,1802240,2883584
// Boff(el): 0,4096,16384,57344,114688,225280,360448
// blocks cum: 8,80,280,672,1320,2288,3640

// ---------------- k_wT: w2 -> per-l B operand layout (scale folded) ----------------
__global__ __launch_bounds__(256) void k_wT(W7 w2, ushort* __restrict__ Bbuf) {
  int ee = blockIdx.x * 256 + threadIdx.x;
  if (ee >= 573440) return;
  int l = (ee >= 4096) + (ee >= 16384) + (ee >= 57344) + (ee >= 114688) +
          (ee >= 225280) + (ee >= 360448);
  int base = sel7(l, 0, 4096, 16384, 57344, 114688, 225280, 360448);
  int d    = sel7(l, 1, 3, 5, 7, 9, 11, 13);
  int Kp   = sel7(l, 64, 64, 128, 128, 192, 192, 256);
  int local = ee - base;
  int row = local / Kp, kcol = local - row * Kp;
  int g2 = row / d, v = row - g2 * d;
  ushort val = 0;
  if (kcol < 16 * d) {
    int f = kcol / d, u = kcol - f * d;
    const float* wl = w2.p[l];
    float scl = rsqrtf(16.f * (float)d);
    val = f2bf(wl[(((size_t)f * 64 + g2) * d + u) * d + v] * scl);
  }
  Bbuf[ee] = val;
}

// ---------------- k_batch: 7 per-l GEMMs, scatter into trajbf ----------------
__global__ __launch_bounds__(256) void k_batch(const ushort* __restrict__ Abuf,
                                               const ushort* __restrict__ Bbuf,
                                               ushort* __restrict__ trajbf) {
  __shared__ __align__(16) short As[64 * 64];
  __shared__ __align__(16) short Bs[64 * 64];
  int bid = blockIdx.x;
  int l = (bid >= 8) + (bid >= 80) + (bid >= 280) + (bid >= 672) +
          (bid >= 1320) + (bid >= 2288);
  int bbase = sel7(l, 0, 8, 80, 280, 672, 1320, 2288);
  int d     = sel7(l, 1, 3, 5, 7, 9, 11, 13);
  int Kp    = sel7(l, 64, 64, 128, 128, 192, 192, 256);
  int o     = sel7(l, 0, 1, 10, 35, 84, 165, 286);
  int Aoff  = sel7(l, 0, 32768, 131072, 458752, 917504, 1802240, 2883584);
  int Boff  = sel7(l, 0, 4096, 16384, 57344, 114688, 225280, 360448);
  int t = bid - bbase;
  int mtile = t / d, ntile = t - mtile * d;

  int tid = threadIdx.x;
  int lane = tid & 63, wid = tid >> 6;
  int quad = lane >> 4, lr = lane & 15;
  int wm = wid >> 1, wn = wid & 1;

  f32x4 acc[2][2];
  #pragma unroll
  for (int a = 0; a < 2; ++a)
    #pragma unroll
    for (int b = 0; b < 2; ++b) acc[a][b] = (f32x4){0.f, 0.f, 0.f, 0.f};

  const ushort* Ab = Abuf + Aoff;
  const ushort* Bb = Bbuf + Boff;

  for (int kc = 0; kc < Kp; kc += 64) {
    __syncthreads();
    #pragma unroll
    for (int it = 0; it < 2; ++it) {
      int s0 = (wid * 2 + it) * 64;
      int s = s0 + lane;
      int r = s >> 3, p8 = s & 7, p = p8 ^ (r & 7);
      const ushort* ga = Ab + (size_t)(mtile * 64 + r) * Kp + kc + p * 8;
      __builtin_amdgcn_global_load_lds(
          (const __attribute__((address_space(1))) u32*)ga,
          (__attribute__((address_space(3))) u32*)(As + s0 * 8), 16, 0, 0);
      const ushort* gb = Bb + (size_t)(ntile * 64 + r) * Kp + kc + p * 8;
      __builtin_amdgcn_global_load_lds(
          (const __attribute__((address_space(1))) u32*)gb,
          (__attribute__((address_space(3))) u32*)(Bs + s0 * 8), 16, 0, 0);
    }
    __syncthreads();
    #pragma unroll
    for (int ks = 0; ks < 2; ++ks) {
      int v = (ks * 4 + quad) ^ (lr & 7);
      bf16x8 af[2], bfv[2];
      #pragma unroll
      for (int mt = 0; mt < 2; ++mt)
        af[mt] = *(const bf16x8*)&As[(wm * 32 + mt * 16 + lr) * 64 + v * 8];
      #pragma unroll
      for (int nt = 0; nt < 2; ++nt)
        bfv[nt] = *(const bf16x8*)&Bs[(wn * 32 + nt * 16 + lr) * 64 + v * 8];
      #pragma unroll
      for (int mt = 0; mt < 2; ++mt)
        #pragma unroll
        for (int nt = 0; nt < 2; ++nt)
          acc[mt][nt] = __builtin_amdgcn_mfma_f32_16x16x32_bf16(af[mt], bfv[nt], acc[mt][nt], 0, 0, 0);
    }
  }
  #pragma unroll
  for (int mt = 0; mt < 2; ++mt)
    #pragma unroll
    for (int nt = 0; nt < 2; ++nt)
      #pragma unroll
      for (int r = 0; r < 4; ++r) {
        int Mrow = mtile * 64 + wm * 32 + mt * 16 + quad * 4 + r;
        int Ncol = ntile * 64 + wn * 32 + nt * 16 + lr;
        int bt = Mrow / d, m = Mrow - bt * d;
        int g2 = Ncol / d, v = Ncol - g2 * d;
        trajbf[(size_t)(bt * 64 + g2) * JP + o + v * d + m] = f2bf(acc[mt][nt][r]);
      }
}

// ---------------- k_ico: blocks [0,512): trajo = trajbf·icoB^T; [512,768): xg = x·icoB^T --
__global__ __launch_bounds__(256) void k_ico(const ushort* __restrict__ trajbf,
                                             const float* __restrict__ x,
                                             const ushort* __restrict__ icoB,
                                             float* __restrict__ trajo,
                                             float* __restrict__ xg) {
  __shared__ __align__(16) short As[64 * 64];
  __shared__ __align__(16) short Bs[64 * 64];
  bool isX = blockIdx.x >= 512;
  int mtile = isX ? (blockIdx.x - 512) : blockIdx.x;
  int tid = threadIdx.x;
  int lane = tid & 63, wid = tid >> 6;
  int quad = lane >> 4, lr = lane & 15;
  int wm = wid >> 1, wn = wid & 1;
  f32x4 acc[2][2];
  #pragma unroll
  for (int a = 0; a < 2; ++a)
    #pragma unroll
    for (int b = 0; b < 2; ++b) acc[a][b] = (f32x4){0.f, 0.f, 0.f, 0.f};
  for (int kc = 0; kc < JP; kc += 64) {
    __syncthreads();
    if (isX) {
      #pragma unroll
      for (int it = 0; it < 2; ++it) {
        int s = it * 256 + tid;
        int r = s >> 3, p8 = s & 7, p = p8 ^ (r & 7);
        const float* xr = x + (size_t)(mtile * 64 + r) * GJ;
        int j0 = kc + p * 8;
        bf16x8 v8;
        #pragma unroll
        for (int jj = 0; jj < 8; ++jj) {
          int j = j0 + jj;
          v8[jj] = (j < GJ) ? (short)f2bf(xr[j]) : (short)0;
        }
        *(bf16x8*)&As[s * 8] = v8;
      }
    } else {
      #pragma unroll
      for (int it = 0; it < 2; ++it) {
        int s0 = (wid * 2 + it) * 64;
        int s = s0 + lane;
        int r = s >> 3, p8 = s & 7, p = p8 ^ (r & 7);
        const ushort* ga = trajbf + (size_t)(mtile * 64 + r) * JP + kc + p * 8;
        __builtin_amdgcn_global_load_lds(
            (const __attribute__((address_space(1))) u32*)ga,
            (__attribute__((address_space(3))) u32*)(As + s0 * 8), 16, 0, 0);
      }
    }
    #pragma unroll
    for (int it = 0; it < 2; ++it) {
      int s0 = (wid * 2 + it) * 64;
      int s = s0 + lane;
      int r = s >> 3, p8 = s & 7, p = p8 ^ (r & 7);
      const ushort* gb = icoB + (size_t)r * JP + kc + p * 8;
      __builtin_amdgcn_global_load_lds(
          (const __attribute__((address_space(1))) u32*)gb,
          (__attribute__((address_space(3))) u32*)(Bs + s0 * 8), 16, 0, 0);
    }
    __syncthreads();
    #pragma unroll
    for (int ks = 0; ks < 2; ++ks) {
      int v = (ks * 4 + quad) ^ (lr & 7);
      bf16x8 af[2], bfv[2];
      #pragma unroll
      for (int mt = 0; mt < 2; ++mt)
        af[mt] = *(const bf16x8*)&As[(wm * 32 + mt * 16 + lr) * 64 + v * 8];
      #pragma unroll
      for (int nt = 0; nt < 2; ++nt)
        bfv[nt] = *(const bf16x8*)&Bs[(wn * 32 + nt * 16 + lr) * 64 + v * 8];
      #pragma unroll
      for (int mt = 0; mt < 2; ++mt)
        #pragma unroll
        for (int nt = 0; nt < 2; ++nt)
          acc[mt][nt] = __builtin_amdgcn_mfma_f32_16x16x32_bf16(af[mt], bfv[nt], acc[mt][nt], 0, 0, 0);
    }
  }
  float* outp = isX ? xg : trajo;
  #pragma unroll
  for (int mt = 0; mt < 2; ++mt)
    #pragma unroll
    for (int nt = 0; nt < 2; ++nt) {
      int i = wn * 32 + nt * 16 + lr;
      if (i < NICO) {
        #pragma unroll
        for (int r = 0; r < 4; ++r) {
          int row = mtile * 64 + wm * 32 + mt * 16 + quad * 4 + r;
          outp[(size_t)row * NICO + i] = acc[mt][nt][r];
        }
      }
    }
}

extern "C" void kernel_launch(void* const* d_in, const int* in_sizes, int n_in,
                              void* d_out, int out_size, void* d_ws, size_t ws_size,
                              hipStream_t stream) {
  const float *x = nullptr, *traj = nullptr, *w1s = nullptr, *w1v = nullptr;
  const float *Din = nullptr, *Dout = nullptr, *ico = nullptr;
  W7 w2{};
  for (int i = 0; i < n_in; ++i) {
    const float* p = (const float*)d_in[i];
    switch (in_sizes[i]) {
      case 7454720: x = p; break;
      case 5120:    traj = p; break;
      case 16:      w1s = p; break;
      case 144:     w1v = p; break;
      case 40960:   Din = p; break;
      case 1863680: Dout = p; break;
      case 27300:   ico = p; break;
      case 1024:    w2.p[0] = p; break;
      case 9216:    w2.p[1] = p; break;
      case 25600:   w2.p[2] = p; break;
      case 50176:   w2.p[3] = p; break;
      case 82944:   w2.p[4] = p; break;
      case 123904:  w2.p[5] = p; break;
      case 173056:  w2.p[6] = p; break;
      default: break;
    }
  }
  // ws layout (bytes), total ~48.5 MB:
  char* wsb = (char*)d_ws;
  float*  h       = (float*)wsb;                       //    327,680 B
  ushort* DoutBT  = (ushort*)(wsb + 327680);           //  4,194,304 B
  ushort* icoB    = (ushort*)(wsb + 4521984);          //     65,536 B
  ushort* Abuf    = (ushort*)(wsb + 4587520);          //  9,175,040 B
  ushort* Bbuf    = (ushort*)(wsb + 13762560);         //  1,146,880 B
  ushort* trajbf  = (ushort*)(wsb + 14909440);         // 33,554,432 B (aliases sigb)
  ushort* sigb    = trajbf;
  float* xg    = (float*)d_out;
  float* trajo = (float*)d_out + 983040;

  hipMemsetAsync(Abuf, 0, 9175040, stream);            // zero K-pad zones of Abuf
  k_hic  <<<dim3(448),    dim3(256), 0, stream>>>(traj, w1s, w1v, ico, h, icoB);
  k_bt   <<<dim3(8, 64),  dim3(256), 0, stream>>>(Dout, DoutBT);
  for (int half = 0; half < 2; ++half) {
    k_sig <<<dim3(2, 256), dim3(256), 0, stream>>>(h + (size_t)half * 40960, Din, sigb);
    k_mm2 <<<dim3(8, 64),  dim3(256), 0, stream>>>(sigb, DoutBT, Abuf, half * 256);
  }
  k_wT   <<<dim3(2240),   dim3(256), 0, stream>>>(w2, Bbuf);
  k_batch<<<dim3(3640),   dim3(256), 0, stream>>>(Abuf, Bbuf, trajbf);
  k_ico  <<<dim3(768),    dim3(256), 0, stream>>>(trajbf, x, icoB, trajo, xg);
}

// Round 6
// 269.958 us; speedup vs baseline: 5.2161x; 1.0426x over previous
//
#include <hip/hip_runtime.h>
#include <math.h>

// EquiGroupSamplingIco — round 6: XCD-aware block swizzle in k_mm2.
// R5 counters showed k_mm2 BW-bound (FETCH 133 MB: A-tile re-read by the 8
// N-blocks landing on 8 different XCDs). Linear grid + decode mb=bid&63,
// nb=bid>>6 puts all 8 sharers of an A-tile on the SAME XCD (bid%8 == mb%8
// under round-robin), all co-resident at 2 blocks/CU -> A fetched ~once.
// Everything else identical to the passing R5 source.

#define NBT  512
#define F8c  16
#define F2c  64
#define GJ   455
#define GG   4096
#define NICO 60
#define JP   512      // padded j for trajbf / icoB

typedef short bf16x8 __attribute__((ext_vector_type(8)));
typedef float f32x4  __attribute__((ext_vector_type(4)));
typedef unsigned int u32;
typedef unsigned short ushort;

struct W7 { const float* p[7]; };

__device__ __forceinline__ ushort f2bf(float f) {
  u32 u = __float_as_uint(f);
  return (ushort)((u + 0x7fffu + ((u >> 16) & 1u)) >> 16);   // RNE
}

__device__ __forceinline__ int sel7(int l, int a0, int a1, int a2, int a3,
                                    int a4, int a5, int a6) {
  int r = a6;
  r = (l == 5) ? a5 : r; r = (l == 4) ? a4 : r; r = (l == 3) ? a3 : r;
  r = (l == 2) ? a2 : r; r = (l == 1) ? a1 : r; r = (l == 0) ? a0 : r;
  return r;
}

// ---------------- k_hic: k_h (blocks 0..319) + icoB build (blocks 320..447) ----------------
__global__ __launch_bounds__(256) void k_hic(const float* __restrict__ traj,
                                             const float* __restrict__ w1s,
                                             const float* __restrict__ w1v,
                                             const float* __restrict__ ico,
                                             float* __restrict__ h,
                                             ushort* __restrict__ icoB) {
  if (blockIdx.x < 320) {
    int idx = blockIdx.x * 256 + threadIdx.x;
    if (idx >= NBT * 160) return;
    int bt = idx / 160, r = idx % 160, c = r / 10, i = r % 10;
    const float* tr = traj + bt * 10;
    float val;
    if (i == 0) {
      val = tr[9] * w1s[c];
    } else {
      int k = i - 1, v = k / 3, m = k % 3;
      float s = 0.f;
      #pragma unroll
      for (int u = 0; u < 3; ++u) s = fmaf(tr[u * 3 + m], w1v[c * 9 + u * 3 + v], s);
      val = s * 0.57735026918962576f;
    }
    h[idx] = val;
  } else {
    int e = (blockIdx.x - 320) * 256 + threadIdx.x;   // 32768
    int i = e >> 9, j = e & 511;
    icoB[e] = (i < NICO && j < GJ) ? f2bf(ico[i * GJ + j]) : (ushort)0;
  }
}

// ---------------- k_bt: DoutBT[j][k] bf16, j padded to 512 ----------------
__global__ __launch_bounds__(256) void k_bt(const float* __restrict__ Dout,
                                            ushort* __restrict__ DoutBT) {
  __shared__ float t[64][65];
  int jt = blockIdx.x, kt = blockIdx.y;
  int tx = threadIdx.x & 63, ty = threadIdx.x >> 6;
  #pragma unroll
  for (int i = 0; i < 16; ++i) {
    int r = i * 4 + ty, j = jt * 64 + tx;
    t[r][tx] = (j < GJ) ? Dout[(size_t)(kt * 64 + r) * GJ + j] : 0.f;
  }
  __syncthreads();
  #pragma unroll
  for (int i = 0; i < 16; ++i) {
    int jl = i * 4 + ty;
    DoutBT[(size_t)(jt * 64 + jl) * GG + kt * 64 + tx] = f2bf(t[tx][jl]);
  }
}

// ---------------- k_sig: sigb[m][k] = bf16(relu(h[m]·Din[k])), one M-half ----------------
__global__ __launch_bounds__(256) void k_sig(const float* __restrict__ h,      // half base
                                             const float* __restrict__ Din,
                                             ushort* __restrict__ sigb) {      // [4096][4096]
  __shared__ float hs[160];
  int tid = threadIdx.x;
  int mb = blockIdx.y;           // 0..255
  int kt = blockIdx.x;           // 0..1
  if (tid < 160) hs[tid] = h[mb * 160 + tid];
  float dr[80];
  const float4* dp = (const float4*)(Din + (size_t)(kt * 2048 + tid * 8) * 10);
  #pragma unroll
  for (int q = 0; q < 20; ++q) {
    float4 v = dp[q];
    dr[q * 4 + 0] = v.x; dr[q * 4 + 1] = v.y; dr[q * 4 + 2] = v.z; dr[q * 4 + 3] = v.w;
  }
  __syncthreads();
  #pragma unroll
  for (int r = 0; r < 16; ++r) {
    float hv[10];
    #pragma unroll
    for (int i = 0; i < 10; ++i) hv[i] = hs[r * 10 + i];
    bf16x8 o;
    #pragma unroll
    for (int j = 0; j < 8; ++j) {
      float s = 0.f;
      #pragma unroll
      for (int i = 0; i < 10; ++i) s = fmaf(hv[i], dr[j * 10 + i], s);
      o[j] = (short)f2bf(fmaxf(s, 0.f));
    }
    *(bf16x8*)&sigb[((size_t)(mb * 16 + r)) * GG + kt * 2048 + tid * 8] = o;
  }
}

// ---------------- k_mm2: (sigb · DoutBT^T) scattered into Abuf, one M-half ----------------
// 64x64 tile, BK=64, dbuf LDS, linear grid 512 with XCD swizzle (see header).
__global__ __launch_bounds__(256) void k_mm2(const ushort* __restrict__ A,     // [4096][4096]
                                             const ushort* __restrict__ Bm,    // [512][4096]
                                             ushort* __restrict__ Abuf,
                                             int btBase) {
  __shared__ __align__(16) short Asb[2][64 * 64];    // 2 x 8 KB
  __shared__ __align__(16) short Bsb[2][64 * 64];    // 2 x 8 KB
  int tid = threadIdx.x;
  int lane = tid & 63, wid = tid >> 6;
  int quad = lane >> 4, lr = lane & 15;
  int wm = wid >> 1, wn = wid & 1;
  int bid = blockIdx.x;
  int mb = bid & 63;             // A-tile: 8 sharers at bid%8==mb%8 -> same XCD
  int nb = bid >> 6;             // B-tile

  f32x4 acc[2][2];
  #pragma unroll
  for (int a = 0; a < 2; ++a)
    #pragma unroll
    for (int b = 0; b < 2; ++b) acc[a][b] = (f32x4){0.f, 0.f, 0.f, 0.f};

  const ushort* Ab = A + (size_t)mb * 64 * GG;
  const ushort* Bb = Bm + (size_t)nb * 64 * GG;

  auto stage = [&](int buf, int kc) {
    #pragma unroll
    for (int it = 0; it < 2; ++it) {                 // A: 512 slots / 4 waves
      int s0 = (wid * 2 + it) * 64;
      int s = s0 + lane;
      int r = s >> 3, pp = s & 7, p = pp ^ (r & 7);
      __builtin_amdgcn_global_load_lds(
          (const __attribute__((address_space(1))) u32*)(Ab + (size_t)r * GG + kc + p * 8),
          (__attribute__((address_space(3))) u32*)(&Asb[buf][s0 * 8]), 16, 0, 0);
    }
    #pragma unroll
    for (int it = 0; it < 2; ++it) {                 // B: 512 slots / 4 waves
      int s0 = (wid * 2 + it) * 64;
      int s = s0 + lane;
      int r = s >> 3, pp = s & 7, p = pp ^ (r & 7);
      __builtin_amdgcn_global_load_lds(
          (const __attribute__((address_space(1))) u32*)(Bb + (size_t)r * GG + kc + p * 8),
          (__attribute__((address_space(3))) u32*)(&Bsb[buf][s0 * 8]), 16, 0, 0);
    }
  };

  stage(0, 0);
  __syncthreads();
  for (int it = 0; it < 64; ++it) {
    int cur = it & 1;
    if (it < 63) stage(cur ^ 1, (it + 1) * 64);
    #pragma unroll
    for (int ks = 0; ks < 2; ++ks) {
      bf16x8 af[2], bv[2];
      #pragma unroll
      for (int mt = 0; mt < 2; ++mt) {
        int ra = wm * 32 + mt * 16 + lr;
        int v = (ks * 4 + quad) ^ (ra & 7);
        af[mt] = *(const bf16x8*)&Asb[cur][(ra * 8 + v) * 8];
      }
      #pragma unroll
      for (int nt = 0; nt < 2; ++nt) {
        int rb = wn * 32 + nt * 16 + lr;
        int v = (ks * 4 + quad) ^ (rb & 7);
        bv[nt] = *(const bf16x8*)&Bsb[cur][(rb * 8 + v) * 8];
      }
      #pragma unroll
      for (int mt = 0; mt < 2; ++mt)
        #pragma unroll
        for (int nt = 0; nt < 2; ++nt)
          acc[mt][nt] = __builtin_amdgcn_mfma_f32_16x16x32_bf16(af[mt], bv[nt], acc[mt][nt], 0, 0, 0);
    }
    __syncthreads();
  }
  // epilogue: scatter bf16 directly into per-l A-operand layout
  #pragma unroll
  for (int nt = 0; nt < 2; ++nt) {
    int j = nb * 64 + wn * 32 + nt * 16 + lr;
    if (j < GJ) {
      int l = (j >= 1) + (j >= 10) + (j >= 35) + (j >= 84) + (j >= 165) + (j >= 286);
      int o    = sel7(l, 0, 1, 10, 35, 84, 165, 286);
      int d    = sel7(l, 1, 3, 5, 7, 9, 11, 13);
      int Kp   = sel7(l, 64, 64, 128, 128, 192, 192, 256);
      int Aoff = sel7(l, 0, 32768, 131072, 458752, 917504, 1802240, 2883584);
      int jl = j - o;
      float rcpd = 1.0f / (float)d;
      int u = (int)(((float)jl + 0.5f) * rcpd);      // exact: margin 0.5/13 >> fp32 eps
      int mB = jl - u * d;
      #pragma unroll
      for (int mt = 0; mt < 2; ++mt)
        #pragma unroll
        for (int r = 0; r < 4; ++r) {
          int m = mb * 64 + wm * 32 + mt * 16 + quad * 4 + r;
          int btg = btBase + (m >> 4), f = m & 15;
          Abuf[(size_t)Aoff + ((size_t)btg * d + mB) * Kp + f * d + u] =
              f2bf(acc[mt][nt][r]);
        }
    }
  }
}

// per-l constants
// d:  1,3,5,7,9,11,13   Kp: 64,64,128,128,192,192,256   o: 0,1,10,35,84,165,286
// Aoff(el): 0,32768,131072,458752,917504,1802240,2883584
// Boff(el): 0,4096,16384,57344,114688,225280,360448
// blocks cum: 8,80,280,672,1320,2288,3640

// ---------------- k_wT: w2 -> per-l B operand layout (scale folded) ----------------
__global__ __launch_bounds__(256) void k_wT(W7 w2, ushort* __restrict__ Bbuf) {
  int ee = blockIdx.x * 256 + threadIdx.x;
  if (ee >= 573440) return;
  int l = (ee >= 4096) + (ee >= 16384) + (ee >= 57344) + (ee >= 114688) +
          (ee >= 225280) + (ee >= 360448);
  int base = sel7(l, 0, 4096, 16384, 57344, 114688, 225280, 360448);
  int d    = sel7(l, 1, 3, 5, 7, 9, 11, 13);
  int Kp   = sel7(l, 64, 64, 128, 128, 192, 192, 256);
  int local = ee - base;
  int row = local / Kp, kcol = local - row * Kp;
  int g2 = row / d, v = row - g2 * d;
  ushort val = 0;
  if (kcol < 16 * d) {
    int f = kcol / d, u = kcol - f * d;
    const float* wl = w2.p[l];
    float scl = rsqrtf(16.f * (float)d);
    val = f2bf(wl[(((size_t)f * 64 + g2) * d + u) * d + v] * scl);
  }
  Bbuf[ee] = val;
}

// ---------------- k_batch: 7 per-l GEMMs, scatter into trajbf ----------------
__global__ __launch_bounds__(256) void k_batch(const ushort* __restrict__ Abuf,
                                               const ushort* __restrict__ Bbuf,
                                               ushort* __restrict__ trajbf) {
  __shared__ __align__(16) short As[64 * 64];
  __shared__ __align__(16) short Bs[64 * 64];
  int bid = blockIdx.x;
  int l = (bid >= 8) + (bid >= 80) + (bid >= 280) + (bid >= 672) +
          (bid >= 1320) + (bid >= 2288);
  int bbase = sel7(l, 0, 8, 80, 280, 672, 1320, 2288);
  int d     = sel7(l, 1, 3, 5, 7, 9, 11, 13);
  int Kp    = sel7(l, 64, 64, 128, 128, 192, 192, 256);
  int o     = sel7(l, 0, 1, 10, 35, 84, 165, 286);
  int Aoff  = sel7(l, 0, 32768, 131072, 458752, 917504, 1802240, 2883584);
  int Boff  = sel7(l, 0, 4096, 16384, 57344, 114688, 225280, 360448);
  int t = bid - bbase;
  int mtile = t / d, ntile = t - mtile * d;

  int tid = threadIdx.x;
  int lane = tid & 63, wid = tid >> 6;
  int quad = lane >> 4, lr = lane & 15;
  int wm = wid >> 1, wn = wid & 1;

  f32x4 acc[2][2];
  #pragma unroll
  for (int a = 0; a < 2; ++a)
    #pragma unroll
    for (int b = 0; b < 2; ++b) acc[a][b] = (f32x4){0.f, 0.f, 0.f, 0.f};

  const ushort* Ab = Abuf + Aoff;
  const ushort* Bb = Bbuf + Boff;

  for (int kc = 0; kc < Kp; kc += 64) {
    __syncthreads();
    #pragma unroll
    for (int it = 0; it < 2; ++it) {
      int s0 = (wid * 2 + it) * 64;
      int s = s0 + lane;
      int r = s >> 3, p8 = s & 7, p = p8 ^ (r & 7);
      const ushort* ga = Ab + (size_t)(mtile * 64 + r) * Kp + kc + p * 8;
      __builtin_amdgcn_global_load_lds(
          (const __attribute__((address_space(1))) u32*)ga,
          (__attribute__((address_space(3))) u32*)(As + s0 * 8), 16, 0, 0);
      const ushort* gb = Bb + (size_t)(ntile * 64 + r) * Kp + kc + p * 8;
      __builtin_amdgcn_global_load_lds(
          (const __attribute__((address_space(1))) u32*)gb,
          (__attribute__((address_space(3))) u32*)(Bs + s0 * 8), 16, 0, 0);
    }
    __syncthreads();
    #pragma unroll
    for (int ks = 0; ks < 2; ++ks) {
      int v = (ks * 4 + quad) ^ (lr & 7);
      bf16x8 af[2], bfv[2];
      #pragma unroll
      for (int mt = 0; mt < 2; ++mt)
        af[mt] = *(const bf16x8*)&As[(wm * 32 + mt * 16 + lr) * 64 + v * 8];
      #pragma unroll
      for (int nt = 0; nt < 2; ++nt)
        bfv[nt] = *(const bf16x8*)&Bs[(wn * 32 + nt * 16 + lr) * 64 + v * 8];
      #pragma unroll
      for (int mt = 0; mt < 2; ++mt)
        #pragma unroll
        for (int nt = 0; nt < 2; ++nt)
          acc[mt][nt] = __builtin_amdgcn_mfma_f32_16x16x32_bf16(af[mt], bfv[nt], acc[mt][nt], 0, 0, 0);
    }
  }
  #pragma unroll
  for (int mt = 0; mt < 2; ++mt)
    #pragma unroll
    for (int nt = 0; nt < 2; ++nt)
      #pragma unroll
      for (int r = 0; r < 4; ++r) {
        int Mrow = mtile * 64 + wm * 32 + mt * 16 + quad * 4 + r;
        int Ncol = ntile * 64 + wn * 32 + nt * 16 + lr;
        int bt = Mrow / d, m = Mrow - bt * d;
        int g2 = Ncol / d, v = Ncol - g2 * d;
        trajbf[(size_t)(bt * 64 + g2) * JP + o + v * d + m] = f2bf(acc[mt][nt][r]);
      }
}

// ---------------- k_ico: blocks [0,512): trajo = trajbf·icoB^T; [512,768): xg = x·icoB^T --
__global__ __launch_bounds__(256) void k_ico(const ushort* __restrict__ trajbf,
                                             const float* __restrict__ x,
                                             const ushort* __restrict__ icoB,
                                             float* __restrict__ trajo,
                                             float* __restrict__ xg) {
  __shared__ __align__(16) short As[64 * 64];
  __shared__ __align__(16) short Bs[64 * 64];
  bool isX = blockIdx.x >= 512;
  int mtile = isX ? (blockIdx.x - 512) : blockIdx.x;
  int tid = threadIdx.x;
  int lane = tid & 63, wid = tid >> 6;
  int quad = lane >> 4, lr = lane & 15;
  int wm = wid >> 1, wn = wid & 1;
  f32x4 acc[2][2];
  #pragma unroll
  for (int a = 0; a < 2; ++a)
    #pragma unroll
    for (int b = 0; b < 2; ++b) acc[a][b] = (f32x4){0.f, 0.f, 0.f, 0.f};
  for (int kc = 0; kc < JP; kc += 64) {
    __syncthreads();
    if (isX) {
      #pragma unroll
      for (int it = 0; it < 2; ++it) {
        int s = it * 256 + tid;
        int r = s >> 3, p8 = s & 7, p = p8 ^ (r & 7);
        const float* xr = x + (size_t)(mtile * 64 + r) * GJ;
        int j0 = kc + p * 8;
        bf16x8 v8;
        #pragma unroll
        for (int jj = 0; jj < 8; ++jj) {
          int j = j0 + jj;
          v8[jj] = (j < GJ) ? (short)f2bf(xr[j]) : (short)0;
        }
        *(bf16x8*)&As[s * 8] = v8;
      }
    } else {
      #pragma unroll
      for (int it = 0; it < 2; ++it) {
        int s0 = (wid * 2 + it) * 64;
        int s = s0 + lane;
        int r = s >> 3, p8 = s & 7, p = p8 ^ (r & 7);
        const ushort* ga = trajbf + (size_t)(mtile * 64 + r) * JP + kc + p * 8;
        __builtin_amdgcn_global_load_lds(
            (const __attribute__((address_space(1))) u32*)ga,
            (__attribute__((address_space(3))) u32*)(As + s0 * 8), 16, 0, 0);
      }
    }
    #pragma unroll
    for (int it = 0; it < 2; ++it) {
      int s0 = (wid * 2 + it) * 64;
      int s = s0 + lane;
      int r = s >> 3, p8 = s & 7, p = p8 ^ (r & 7);
      const ushort* gb = icoB + (size_t)r * JP + kc + p * 8;
      __builtin_amdgcn_global_load_lds(
          (const __attribute__((address_space(1))) u32*)gb,
          (__attribute__((address_space(3))) u32*)(Bs + s0 * 8), 16, 0, 0);
    }
    __syncthreads();
    #pragma unroll
    for (int ks = 0; ks < 2; ++ks) {
      int v = (ks * 4 + quad) ^ (lr & 7);
      bf16x8 af[2], bfv[2];
      #pragma unroll
      for (int mt = 0; mt < 2; ++mt)
        af[mt] = *(const bf16x8*)&As[(wm * 32 + mt * 16 + lr) * 64 + v * 8];
      #pragma unroll
      for (int nt = 0; nt < 2; ++nt)
        bfv[nt] = *(const bf16x8*)&Bs[(wn * 32 + nt * 16 + lr) * 64 + v * 8];
      #pragma unroll
      for (int mt = 0; mt < 2; ++mt)
        #pragma unroll
        for (int nt = 0; nt < 2; ++nt)
          acc[mt][nt] = __builtin_amdgcn_mfma_f32_16x16x32_bf16(af[mt], bfv[nt], acc[mt][nt], 0, 0, 0);
    }
  }
  float* outp = isX ? xg : trajo;
  #pragma unroll
  for (int mt = 0; mt < 2; ++mt)
    #pragma unroll
    for (int nt = 0; nt < 2; ++nt) {
      int i = wn * 32 + nt * 16 + lr;
      if (i < NICO) {
        #pragma unroll
        for (int r = 0; r < 4; ++r) {
          int row = mtile * 64 + wm * 32 + mt * 16 + quad * 4 + r;
          outp[(size_t)row * NICO + i] = acc[mt][nt][r];
        }
      }
    }
}

extern "C" void kernel_launch(void* const* d_in, const int* in_sizes, int n_in,
                              void* d_out, int out_size, void* d_ws, size_t ws_size,
                              hipStream_t stream) {
  const float *x = nullptr, *traj = nullptr, *w1s = nullptr, *w1v = nullptr;
  const float *Din = nullptr, *Dout = nullptr, *ico = nullptr;
  W7 w2{};
  for (int i = 0; i < n_in; ++i) {
    const float* p = (const float*)d_in[i];
    switch (in_sizes[i]) {
      case 7454720: x = p; break;
      case 5120:    traj = p; break;
      case 16:      w1s = p; break;
      case 144:     w1v = p; break;
      case 40960:   Din = p; break;
      case 1863680: Dout = p; break;
      case 27300:   ico = p; break;
      case 1024:    w2.p[0] = p; break;
      case 9216:    w2.p[1] = p; break;
      case 25600:   w2.p[2] = p; break;
      case 50176:   w2.p[3] = p; break;
      case 82944:   w2.p[4] = p; break;
      case 123904:  w2.p[5] = p; break;
      case 173056:  w2.p[6] = p; break;
      default: break;
    }
  }
  // ws layout (bytes), total ~48.5 MB:
  char* wsb = (char*)d_ws;
  float*  h       = (float*)wsb;                       //    327,680 B
  ushort* DoutBT  = (ushort*)(wsb + 327680);           //  4,194,304 B
  ushort* icoB    = (ushort*)(wsb + 4521984);          //     65,536 B
  ushort* Abuf    = (ushort*)(wsb + 4587520);          //  9,175,040 B
  ushort* Bbuf    = (ushort*)(wsb + 13762560);         //  1,146,880 B
  ushort* trajbf  = (ushort*)(wsb + 14909440);         // 33,554,432 B (aliases sigb)
  ushort* sigb    = trajbf;
  float* xg    = (float*)d_out;
  float* trajo = (float*)d_out + 983040;

  hipMemsetAsync(Abuf, 0, 9175040, stream);            // zero K-pad zones of Abuf
  k_hic  <<<dim3(448),    dim3(256), 0, stream>>>(traj, w1s, w1v, ico, h, icoB);
  k_bt   <<<dim3(8, 64),  dim3(256), 0, stream>>>(Dout, DoutBT);
  for (int half = 0; half < 2; ++half) {
    k_sig <<<dim3(2, 256), dim3(256), 0, stream>>>(h + (size_t)half * 40960, Din, sigb);
    k_mm2 <<<dim3(512),    dim3(256), 0, stream>>>(sigb, DoutBT, Abuf, half * 256);
  }
  k_wT   <<<dim3(2240),   dim3(256), 0, stream>>>(w2, Bbuf);
  k_batch<<<dim3(3640),   dim3(256), 0, stream>>>(Abuf, Bbuf, trajbf);
  k_ico  <<<dim3(768),    dim3(256), 0, stream>>>(trajbf, x, icoB, trajo, xg);
}

// Round 7
// 261.945 us; speedup vs baseline: 5.3757x; 1.0306x over previous
//
#include <hip/hip_runtime.h>
#include <math.h>

// EquiGroupSamplingIco — round 7:
//  - k_mm2 retiled to 128x128 (4 waves x 64x64 wave tile, 4x4 acc, BK=64, dbuf
//    64KB LDS): halves LDS bytes/FLOP vs 64x64 (R6 showed LDS-throughput bound).
//    Both M-halves in ONE launch (grid 256, XCD decode mb=bid&63) when ws_size
//    allows the 67MB sigb; otherwise per-half fallback with the same kernels.
//  - Dispatch fusion: k_pre = {Abuf zero, k_bt, k_wT, k_h, icoB} (5440 blocks);
//    k_batchX = k_batch + xg GEMM; k_icoT = trajo GEMM. 10 -> 5 dispatches.

#define NBT  512
#define F8c  16
#define F2c  64
#define GJ   455
#define GG   4096
#define NICO 60
#define JP   512      // padded j for trajbf / icoB

typedef short bf16x8 __attribute__((ext_vector_type(8)));
typedef float f32x4  __attribute__((ext_vector_type(4)));
typedef unsigned int u32;
typedef unsigned short ushort;

struct W7 { const float* p[7]; };

__device__ __forceinline__ ushort f2bf(float f) {
  u32 u = __float_as_uint(f);
  return (ushort)((u + 0x7fffu + ((u >> 16) & 1u)) >> 16);   // RNE
}

__device__ __forceinline__ int sel7(int l, int a0, int a1, int a2, int a3,
                                    int a4, int a5, int a6) {
  int r = a6;
  r = (l == 5) ? a5 : r; r = (l == 4) ? a4 : r; r = (l == 3) ? a3 : r;
  r = (l == 2) ? a2 : r; r = (l == 1) ? a1 : r; r = (l == 0) ? a0 : r;
  return r;
}

// ---------------- k_pre: fused preprocessing ----------------
// [0,2240)    zero Abuf (uint4)
// [2240,2752) k_bt: DoutBT[j][k] bf16 (j padded to 512)
// [2752,4992) k_wT: w2 -> per-l B operand layout (scale folded)
// [4992,5312) k_h : h[bt][c][i]
// [5312,5440) icoB[i][j] bf16 64x512 zero-padded
__global__ __launch_bounds__(256) void k_pre(const float* __restrict__ traj,
                                             const float* __restrict__ w1s,
                                             const float* __restrict__ w1v,
                                             const float* __restrict__ ico,
                                             const float* __restrict__ Dout,
                                             W7 w2,
                                             float* __restrict__ h,
                                             ushort* __restrict__ icoB,
                                             ushort* __restrict__ DoutBT,
                                             ushort* __restrict__ Abuf,
                                             ushort* __restrict__ Bbuf) {
  __shared__ float t[64][65];
  int b = blockIdx.x, tid = threadIdx.x;
  if (b < 2240) {
    ((uint4*)Abuf)[b * 256 + tid] = (uint4){0, 0, 0, 0};
  } else if (b < 2752) {
    int b2 = b - 2240;
    int jt = b2 & 7, kt = b2 >> 3;
    int tx = tid & 63, ty = tid >> 6;
    #pragma unroll
    for (int i = 0; i < 16; ++i) {
      int r = i * 4 + ty, j = jt * 64 + tx;
      t[r][tx] = (j < GJ) ? Dout[(size_t)(kt * 64 + r) * GJ + j] : 0.f;
    }
    __syncthreads();
    #pragma unroll
    for (int i = 0; i < 16; ++i) {
      int jl = i * 4 + ty;
      DoutBT[(size_t)(jt * 64 + jl) * GG + kt * 64 + tx] = f2bf(t[tx][jl]);
    }
  } else if (b < 4992) {
    int ee = (b - 2752) * 256 + tid;
    if (ee < 573440) {
      int l = (ee >= 4096) + (ee >= 16384) + (ee >= 57344) + (ee >= 114688) +
              (ee >= 225280) + (ee >= 360448);
      int base = sel7(l, 0, 4096, 16384, 57344, 114688, 225280, 360448);
      int d    = sel7(l, 1, 3, 5, 7, 9, 11, 13);
      int Kp   = sel7(l, 64, 64, 128, 128, 192, 192, 256);
      int local = ee - base;
      int row = local / Kp, kcol = local - row * Kp;
      int g2 = row / d, v = row - g2 * d;
      ushort val = 0;
      if (kcol < 16 * d) {
        int f = kcol / d, u = kcol - f * d;
        const float* wl = w2.p[l];
        float scl = rsqrtf(16.f * (float)d);
        val = f2bf(wl[(((size_t)f * 64 + g2) * d + u) * d + v] * scl);
      }
      Bbuf[ee] = val;
    }
  } else if (b < 5312) {
    int idx = (b - 4992) * 256 + tid;
    if (idx < NBT * 160) {
      int bt = idx / 160, r = idx % 160, c = r / 10, i = r % 10;
      const float* tr = traj + bt * 10;
      float val;
      if (i == 0) {
        val = tr[9] * w1s[c];
      } else {
        int k = i - 1, v = k / 3, m = k % 3;
        float s = 0.f;
        #pragma unroll
        for (int u = 0; u < 3; ++u) s = fmaf(tr[u * 3 + m], w1v[c * 9 + u * 3 + v], s);
        val = s * 0.57735026918962576f;
      }
      h[idx] = val;
    }
  } else {
    int e = (b - 5312) * 256 + tid;   // 32768
    int i = e >> 9, j = e & 511;
    icoB[e] = (i < NICO && j < GJ) ? f2bf(ico[i * GJ + j]) : (ushort)0;
  }
}

// ---------------- k_sig: sigb[m][k] = bf16(relu(h[m]·Din[k])) ----------------
__global__ __launch_bounds__(256) void k_sig(const float* __restrict__ h,
                                             const float* __restrict__ Din,
                                             ushort* __restrict__ sigb) {
  __shared__ float hs[160];
  int tid = threadIdx.x;
  int mb = blockIdx.y;
  int kt = blockIdx.x;           // 0..1
  if (tid < 160) hs[tid] = h[mb * 160 + tid];
  float dr[80];
  const float4* dp = (const float4*)(Din + (size_t)(kt * 2048 + tid * 8) * 10);
  #pragma unroll
  for (int q = 0; q < 20; ++q) {
    float4 v = dp[q];
    dr[q * 4 + 0] = v.x; dr[q * 4 + 1] = v.y; dr[q * 4 + 2] = v.z; dr[q * 4 + 3] = v.w;
  }
  __syncthreads();
  #pragma unroll
  for (int r = 0; r < 16; ++r) {
    float hv[10];
    #pragma unroll
    for (int i = 0; i < 10; ++i) hv[i] = hs[r * 10 + i];
    bf16x8 o;
    #pragma unroll
    for (int j = 0; j < 8; ++j) {
      float s = 0.f;
      #pragma unroll
      for (int i = 0; i < 10; ++i) s = fmaf(hv[i], dr[j * 10 + i], s);
      o[j] = (short)f2bf(fmaxf(s, 0.f));
    }
    *(bf16x8*)&sigb[((size_t)(mb * 16 + r)) * GG + kt * 2048 + tid * 8] = o;
  }
}

// ---------------- k_mm2: (sigb · DoutBT^T) scattered into Abuf ----------------
// 128x128 tile, BK=64, 4 waves (2x2, wave tile 64x64, 4x4 acc), dbuf LDS 64KB.
// Linear grid, decode mb = bid & ((1<<mbShift)-1) -> A-tile sharers on same XCD.
__global__ __launch_bounds__(256) void k_mm2(const ushort* __restrict__ A,
                                             const ushort* __restrict__ Bm,    // [512][4096]
                                             ushort* __restrict__ Abuf,
                                             int btBase, int mbShift) {
  __shared__ __align__(16) short Asb[2][128 * 64];   // 2 x 16 KB
  __shared__ __align__(16) short Bsb[2][128 * 64];   // 2 x 16 KB
  int tid = threadIdx.x;
  int lane = tid & 63, wid = tid >> 6;
  int quad = lane >> 4, lr = lane & 15;
  int wm = wid >> 1, wn = wid & 1;                   // wave tile: rows wm*64, cols wn*64
  int bid = blockIdx.x;
  int mb = bid & ((1 << mbShift) - 1);
  int nb = bid >> mbShift;

  f32x4 acc[4][4];
  #pragma unroll
  for (int a = 0; a < 4; ++a)
    #pragma unroll
    for (int b = 0; b < 4; ++b) acc[a][b] = (f32x4){0.f, 0.f, 0.f, 0.f};

  const ushort* Ab = A + (size_t)mb * 128 * GG;
  const ushort* Bb = Bm + (size_t)nb * 128 * GG;

  auto stage = [&](int buf, int kc) {
    #pragma unroll
    for (int it = 0; it < 4; ++it) {                 // A: 1024 slots / 4 waves
      int s0 = (wid * 4 + it) * 64;
      int s = s0 + lane;
      int r = s >> 3, pp = s & 7, p = pp ^ (r & 7);
      __builtin_amdgcn_global_load_lds(
          (const __attribute__((address_space(1))) u32*)(Ab + (size_t)r * GG + kc + p * 8),
          (__attribute__((address_space(3))) u32*)(&Asb[buf][s0 * 8]), 16, 0, 0);
    }
    #pragma unroll
    for (int it = 0; it < 4; ++it) {                 // B: 1024 slots / 4 waves
      int s0 = (wid * 4 + it) * 64;
      int s = s0 + lane;
      int r = s >> 3, pp = s & 7, p = pp ^ (r & 7);
      __builtin_amdgcn_global_load_lds(
          (const __attribute__((address_space(1))) u32*)(Bb + (size_t)r * GG + kc + p * 8),
          (__attribute__((address_space(3))) u32*)(&Bsb[buf][s0 * 8]), 16, 0, 0);
    }
  };

  stage(0, 0);
  __syncthreads();
  for (int it = 0; it < 64; ++it) {
    int cur = it & 1;
    if (it < 63) stage(cur ^ 1, (it + 1) * 64);      // in flight across compute phase
    #pragma unroll
    for (int ks = 0; ks < 2; ++ks) {
      bf16x8 af[4], bv[4];
      #pragma unroll
      for (int mt = 0; mt < 4; ++mt) {
        int ra = wm * 64 + mt * 16 + lr;
        int v = (ks * 4 + quad) ^ (ra & 7);
        af[mt] = *(const bf16x8*)&Asb[cur][(ra * 8 + v) * 8];
      }
      #pragma unroll
      for (int nt = 0; nt < 4; ++nt) {
        int rb = wn * 64 + nt * 16 + lr;
        int v = (ks * 4 + quad) ^ (rb & 7);
        bv[nt] = *(const bf16x8*)&Bsb[cur][(rb * 8 + v) * 8];
      }
      #pragma unroll
      for (int mt = 0; mt < 4; ++mt)
        #pragma unroll
        for (int nt = 0; nt < 4; ++nt)
          acc[mt][nt] = __builtin_amdgcn_mfma_f32_16x16x32_bf16(af[mt], bv[nt], acc[mt][nt], 0, 0, 0);
    }
    __syncthreads();
  }
  // epilogue: scatter bf16 directly into per-l A-operand layout
  #pragma unroll
  for (int nt = 0; nt < 4; ++nt) {
    int j = nb * 128 + wn * 64 + nt * 16 + lr;
    if (j < GJ) {
      int l = (j >= 1) + (j >= 10) + (j >= 35) + (j >= 84) + (j >= 165) + (j >= 286);
      int o    = sel7(l, 0, 1, 10, 35, 84, 165, 286);
      int d    = sel7(l, 1, 3, 5, 7, 9, 11, 13);
      int Kp   = sel7(l, 64, 64, 128, 128, 192, 192, 256);
      int Aoff = sel7(l, 0, 32768, 131072, 458752, 917504, 1802240, 2883584);
      int jl = j - o;
      float rcpd = 1.0f / (float)d;
      int u = (int)(((float)jl + 0.5f) * rcpd);      // exact: margin 0.5/13 >> fp32 eps
      int mB = jl - u * d;
      #pragma unroll
      for (int mt = 0; mt < 4; ++mt)
        #pragma unroll
        for (int r = 0; r < 4; ++r) {
          int m = mb * 128 + wm * 64 + mt * 16 + quad * 4 + r;
          int btg = btBase + (m >> 4), f = m & 15;
          Abuf[(size_t)Aoff + ((size_t)btg * d + mB) * Kp + f * d + u] =
              f2bf(acc[mt][nt][r]);
        }
    }
  }
}

// ---------------- k_batchX: [0,3640) per-l GEMMs -> trajbf; [3640,3896) xg GEMM --------
__global__ __launch_bounds__(256) void k_batchX(const ushort* __restrict__ Abuf,
                                                const ushort* __restrict__ Bbuf,
                                                const float* __restrict__ x,
                                                const ushort* __restrict__ icoB,
                                                ushort* __restrict__ trajbf,
                                                float* __restrict__ xg) {
  __shared__ __align__(16) short As[64 * 64];
  __shared__ __align__(16) short Bs[64 * 64];
  int bid = blockIdx.x;
  int tid = threadIdx.x;
  int lane = tid & 63, wid = tid >> 6;
  int quad = lane >> 4, lr = lane & 15;
  int wm = wid >> 1, wn = wid & 1;
  f32x4 acc[2][2];
  #pragma unroll
  for (int a = 0; a < 2; ++a)
    #pragma unroll
    for (int b = 0; b < 2; ++b) acc[a][b] = (f32x4){0.f, 0.f, 0.f, 0.f};

  if (bid >= 3640) {
    // xg = x · icoB^T, inline fp32->bf16 staging
    int mtile = bid - 3640;
    for (int kc = 0; kc < JP; kc += 64) {
      __syncthreads();
      #pragma unroll
      for (int it = 0; it < 2; ++it) {
        int s = it * 256 + tid;
        int r = s >> 3, p8 = s & 7, p = p8 ^ (r & 7);
        const float* xr = x + (size_t)(mtile * 64 + r) * GJ;
        int j0 = kc + p * 8;
        bf16x8 v8;
        #pragma unroll
        for (int jj = 0; jj < 8; ++jj) {
          int j = j0 + jj;
          v8[jj] = (j < GJ) ? (short)f2bf(xr[j]) : (short)0;
        }
        *(bf16x8*)&As[s * 8] = v8;
      }
      #pragma unroll
      for (int it = 0; it < 2; ++it) {
        int s0 = (wid * 2 + it) * 64;
        int s = s0 + lane;
        int r = s >> 3, p8 = s & 7, p = p8 ^ (r & 7);
        const ushort* gb = icoB + (size_t)r * JP + kc + p * 8;
        __builtin_amdgcn_global_load_lds(
            (const __attribute__((address_space(1))) u32*)gb,
            (__attribute__((address_space(3))) u32*)(Bs + s0 * 8), 16, 0, 0);
      }
      __syncthreads();
      #pragma unroll
      for (int ks = 0; ks < 2; ++ks) {
        int v = (ks * 4 + quad) ^ (lr & 7);
        bf16x8 af[2], bfv[2];
        #pragma unroll
        for (int mt = 0; mt < 2; ++mt)
          af[mt] = *(const bf16x8*)&As[(wm * 32 + mt * 16 + lr) * 64 + v * 8];
        #pragma unroll
        for (int nt = 0; nt < 2; ++nt)
          bfv[nt] = *(const bf16x8*)&Bs[(wn * 32 + nt * 16 + lr) * 64 + v * 8];
        #pragma unroll
        for (int mt = 0; mt < 2; ++mt)
          #pragma unroll
          for (int nt = 0; nt < 2; ++nt)
            acc[mt][nt] = __builtin_amdgcn_mfma_f32_16x16x32_bf16(af[mt], bfv[nt], acc[mt][nt], 0, 0, 0);
      }
    }
    #pragma unroll
    for (int mt = 0; mt < 2; ++mt)
      #pragma unroll
      for (int nt = 0; nt < 2; ++nt) {
        int i = wn * 32 + nt * 16 + lr;
        if (i < NICO) {
          #pragma unroll
          for (int r = 0; r < 4; ++r) {
            int row = mtile * 64 + wm * 32 + mt * 16 + quad * 4 + r;
            xg[(size_t)row * NICO + i] = acc[mt][nt][r];
          }
        }
      }
    return;
  }

  int l = (bid >= 8) + (bid >= 80) + (bid >= 280) + (bid >= 672) +
          (bid >= 1320) + (bid >= 2288);
  int bbase = sel7(l, 0, 8, 80, 280, 672, 1320, 2288);
  int d     = sel7(l, 1, 3, 5, 7, 9, 11, 13);
  int Kp    = sel7(l, 64, 64, 128, 128, 192, 192, 256);
  int o     = sel7(l, 0, 1, 10, 35, 84, 165, 286);
  int Aoff  = sel7(l, 0, 32768, 131072, 458752, 917504, 1802240, 2883584);
  int Boff  = sel7(l, 0, 4096, 16384, 57344, 114688, 225280, 360448);
  int t = bid - bbase;
  int mtile = t / d, ntile = t - mtile * d;

  const ushort* Ab = Abuf + Aoff;
  const ushort* Bb = Bbuf + Boff;

  for (int kc = 0; kc < Kp; kc += 64) {
    __syncthreads();
    #pragma unroll
    for (int it = 0; it < 2; ++it) {
      int s0 = (wid * 2 + it) * 64;
      int s = s0 + lane;
      int r = s >> 3, p8 = s & 7, p = p8 ^ (r & 7);
      const ushort* ga = Ab + (size_t)(mtile * 64 + r) * Kp + kc + p * 8;
      __builtin_amdgcn_global_load_lds(
          (const __attribute__((address_space(1))) u32*)ga,
          (__attribute__((address_space(3))) u32*)(As + s0 * 8), 16, 0, 0);
      const ushort* gb = Bb + (size_t)(ntile * 64 + r) * Kp + kc + p * 8;
      __builtin_amdgcn_global_load_lds(
          (const __attribute__((address_space(1))) u32*)gb,
          (__attribute__((address_space(3))) u32*)(Bs + s0 * 8), 16, 0, 0);
    }
    __syncthreads();
    #pragma unroll
    for (int ks = 0; ks < 2; ++ks) {
      int v = (ks * 4 + quad) ^ (lr & 7);
      bf16x8 af[2], bfv[2];
      #pragma unroll
      for (int mt = 0; mt < 2; ++mt)
        af[mt] = *(const bf16x8*)&As[(wm * 32 + mt * 16 + lr) * 64 + v * 8];
      #pragma unroll
      for (int nt = 0; nt < 2; ++nt)
        bfv[nt] = *(const bf16x8*)&Bs[(wn * 32 + nt * 16 + lr) * 64 + v * 8];
      #pragma unroll
      for (int mt = 0; mt < 2; ++mt)
        #pragma unroll
        for (int nt = 0; nt < 2; ++nt)
          acc[mt][nt] = __builtin_amdgcn_mfma_f32_16x16x32_bf16(af[mt], bfv[nt], acc[mt][nt], 0, 0, 0);
    }
  }
  #pragma unroll
  for (int mt = 0; mt < 2; ++mt)
    #pragma unroll
    for (int nt = 0; nt < 2; ++nt)
      #pragma unroll
      for (int r = 0; r < 4; ++r) {
        int Mrow = mtile * 64 + wm * 32 + mt * 16 + quad * 4 + r;
        int Ncol = ntile * 64 + wn * 32 + nt * 16 + lr;
        int bt = Mrow / d, m = Mrow - bt * d;
        int g2 = Ncol / d, v = Ncol - g2 * d;
        trajbf[(size_t)(bt * 64 + g2) * JP + o + v * d + m] = f2bf(acc[mt][nt][r]);
      }
}

// ---------------- k_icoT: trajo = trajbf · icoB^T ----------------
__global__ __launch_bounds__(256) void k_icoT(const ushort* __restrict__ trajbf,
                                              const ushort* __restrict__ icoB,
                                              float* __restrict__ trajo) {
  __shared__ __align__(16) short As[64 * 64];
  __shared__ __align__(16) short Bs[64 * 64];
  int mtile = blockIdx.x;
  int tid = threadIdx.x;
  int lane = tid & 63, wid = tid >> 6;
  int quad = lane >> 4, lr = lane & 15;
  int wm = wid >> 1, wn = wid & 1;
  f32x4 acc[2][2];
  #pragma unroll
  for (int a = 0; a < 2; ++a)
    #pragma unroll
    for (int b = 0; b < 2; ++b) acc[a][b] = (f32x4){0.f, 0.f, 0.f, 0.f};
  for (int kc = 0; kc < JP; kc += 64) {
    __syncthreads();
    #pragma unroll
    for (int it = 0; it < 2; ++it) {
      int s0 = (wid * 2 + it) * 64;
      int s = s0 + lane;
      int r = s >> 3, p8 = s & 7, p = p8 ^ (r & 7);
      const ushort* ga = trajbf + (size_t)(mtile * 64 + r) * JP + kc + p * 8;
      __builtin_amdgcn_global_load_lds(
          (const __attribute__((address_space(1))) u32*)ga,
          (__attribute__((address_space(3))) u32*)(As + s0 * 8), 16, 0, 0);
      const ushort* gb = icoB + (size_t)r * JP + kc + p * 8;
      __builtin_amdgcn_global_load_lds(
          (const __attribute__((address_space(1))) u32*)gb,
          (__attribute__((address_space(3))) u32*)(Bs + s0 * 8), 16, 0, 0);
    }
    __syncthreads();
    #pragma unroll
    for (int ks = 0; ks < 2; ++ks) {
      int v = (ks * 4 + quad) ^ (lr & 7);
      bf16x8 af[2], bfv[2];
      #pragma unroll
      for (int mt = 0; mt < 2; ++mt)
        af[mt] = *(const bf16x8*)&As[(wm * 32 + mt * 16 + lr) * 64 + v * 8];
      #pragma unroll
      for (int nt = 0; nt < 2; ++nt)
        bfv[nt] = *(const bf16x8*)&Bs[(wn * 32 + nt * 16 + lr) * 64 + v * 8];
      #pragma unroll
      for (int mt = 0; mt < 2; ++mt)
        #pragma unroll
        for (int nt = 0; nt < 2; ++nt)
          acc[mt][nt] = __builtin_amdgcn_mfma_f32_16x16x32_bf16(af[mt], bfv[nt], acc[mt][nt], 0, 0, 0);
    }
  }
  #pragma unroll
  for (int mt = 0; mt < 2; ++mt)
    #pragma unroll
    for (int nt = 0; nt < 2; ++nt) {
      int i = wn * 32 + nt * 16 + lr;
      if (i < NICO) {
        #pragma unroll
        for (int r = 0; r < 4; ++r) {
          int row = mtile * 64 + wm * 32 + mt * 16 + quad * 4 + r;
          trajo[(size_t)row * NICO + i] = acc[mt][nt][r];
        }
      }
    }
}

extern "C" void kernel_launch(void* const* d_in, const int* in_sizes, int n_in,
                              void* d_out, int out_size, void* d_ws, size_t ws_size,
                              hipStream_t stream) {
  const float *x = nullptr, *traj = nullptr, *w1s = nullptr, *w1v = nullptr;
  const float *Din = nullptr, *Dout = nullptr, *ico = nullptr;
  W7 w2{};
  for (int i = 0; i < n_in; ++i) {
    const float* p = (const float*)d_in[i];
    switch (in_sizes[i]) {
      case 7454720: x = p; break;
      case 5120:    traj = p; break;
      case 16:      w1s = p; break;
      case 144:     w1v = p; break;
      case 40960:   Din = p; break;
      case 1863680: Dout = p; break;
      case 27300:   ico = p; break;
      case 1024:    w2.p[0] = p; break;
      case 9216:    w2.p[1] = p; break;
      case 25600:   w2.p[2] = p; break;
      case 50176:   w2.p[3] = p; break;
      case 82944:   w2.p[4] = p; break;
      case 123904:  w2.p[5] = p; break;
      case 173056:  w2.p[6] = p; break;
      default: break;
    }
  }
  // ws layout (bytes):
  //   h       @ 0          (327,680)
  //   DoutBT  @ 327,680    (4,194,304)
  //   icoB    @ 4,521,984  (65,536)
  //   Abuf    @ 4,587,520  (9,175,040)
  //   Bbuf    @ 13,762,560 (1,146,880)
  //   sigb    @ 14,909,440 (67,108,864 combined / 33,554,432 per-half)
  //   trajbf  = sigb base (alias; written only after k_mm2 consumed sigb)
  // combined total 82,018,304 B; fallback total 48,463,872 B (R5/R6-proven).
  char* wsb = (char*)d_ws;
  float*  h       = (float*)wsb;
  ushort* DoutBT  = (ushort*)(wsb + 327680);
  ushort* icoB    = (ushort*)(wsb + 4521984);
  ushort* Abuf    = (ushort*)(wsb + 4587520);
  ushort* Bbuf    = (ushort*)(wsb + 13762560);
  ushort* sigb    = (ushort*)(wsb + 14909440);
  ushort* trajbf  = sigb;
  float* xg    = (float*)d_out;
  float* trajo = (float*)d_out + 983040;

  k_pre<<<dim3(5440), dim3(256), 0, stream>>>(traj, w1s, w1v, ico, Dout, w2,
                                              h, icoB, DoutBT, Abuf, Bbuf);
  if (ws_size >= 82018304ULL) {
    // combined: M=8192 in one GEMM launch (grid 256 = 64 mtiles x 4 nb)
    k_sig<<<dim3(2, 512), dim3(256), 0, stream>>>(h, Din, sigb);
    k_mm2<<<dim3(256),    dim3(256), 0, stream>>>(sigb, DoutBT, Abuf, 0, 6);
  } else {
    for (int half = 0; half < 2; ++half) {
      k_sig<<<dim3(2, 256), dim3(256), 0, stream>>>(h + (size_t)half * 40960, Din, sigb);
      k_mm2<<<dim3(128),    dim3(256), 0, stream>>>(sigb, DoutBT, Abuf, half * 256, 5);
    }
  }
  k_batchX<<<dim3(3896), dim3(256), 0, stream>>>(Abuf, Bbuf, x, icoB, trajbf, xg);
  k_icoT  <<<dim3(512),  dim3(256), 0, stream>>>(trajbf, icoB, trajo);
}